// Round 1
// baseline (980.025 us; speedup 1.0000x reference)
//
#include <hip/hip_runtime.h>
#include <hip/hip_bf16.h>
#include <cstdint>

#define NND 100000
#define NED 1600000
#define FIN 128
#define FOUT 64

// ---------------- degree count ----------------
__global__ __launch_bounds__(256) void k_deg(const int* __restrict__ dst,
                                             int* __restrict__ deg, int e) {
    int i = blockIdx.x * 256 + threadIdx.x;
    if (i < e) atomicAdd(&deg[dst[i]], 1);
}

// ---------------- exclusive scan over N (single block) ----------------
__global__ __launch_bounds__(1024) void k_scan(const int* __restrict__ deg,
                                               int* __restrict__ offs,
                                               float* __restrict__ dinv, int n) {
    __shared__ int part[1024];
    const int tid = threadIdx.x;
    const int per = (n + 1023) / 1024;
    const int s = tid * per;
    const int e = min(s + per, n);
    int sum = 0;
    for (int i = s; i < e; i++) sum += deg[i];
    part[tid] = sum;
    __syncthreads();
    for (int off = 1; off < 1024; off <<= 1) {
        int v = (tid >= off) ? part[tid - off] : 0;
        __syncthreads();
        part[tid] += v;
        __syncthreads();
    }
    int run = part[tid] - sum;  // exclusive prefix of this thread's chunk
    for (int i = s; i < e; i++) {
        int d = deg[i];
        offs[i] = run;
        run += d;
        dinv[i] = 1.0f / fmaxf((float)d, 1.0f);
    }
    if (tid == 1023) offs[n] = part[1023];
}

// ---------------- CSR fill (counting sort by dst) ----------------
__global__ __launch_bounds__(256) void k_csr(const int* __restrict__ src,
                                             const int* __restrict__ dst,
                                             const int* __restrict__ offs,
                                             int* __restrict__ cursor,
                                             int* __restrict__ csr, int e) {
    int i = blockIdx.x * 256 + threadIdx.x;
    if (i < e) {
        int d = dst[i];
        int pos = offs[d] + atomicAdd(&cursor[d], 1);
        csr[pos] = src[i];
    }
}

// ---------------- mean-aggregate: one wave per node ----------------
__global__ __launch_bounds__(256) void k_agg(const float* __restrict__ feat,
                                             const int* __restrict__ offs,
                                             const int* __restrict__ csr,
                                             const float* __restrict__ dinv,
                                             float* __restrict__ out, int n) {
    int node = blockIdx.x * 4 + (threadIdx.x >> 6);
    if (node >= n) return;
    int lane = threadIdx.x & 63;
    int beg = offs[node], end = offs[node + 1];
    const float2* f2 = (const float2*)feat;
    float2 acc = make_float2(0.f, 0.f);
    int i = beg;
    for (; i + 1 < end; i += 2) {   // 2-edge unroll for a little MLP
        int s0 = csr[i], s1 = csr[i + 1];
        float2 v0 = f2[(size_t)s0 * 64 + lane];
        float2 v1 = f2[(size_t)s1 * 64 + lane];
        acc.x += v0.x + v1.x;
        acc.y += v0.y + v1.y;
    }
    if (i < end) {
        int s0 = csr[i];
        float2 v0 = f2[(size_t)s0 * 64 + lane];
        acc.x += v0.x;
        acc.y += v0.y;
    }
    float di = dinv[node];
    ((float2*)out)[(size_t)node * 64 + lane] = make_float2(acc.x * di, acc.y * di);
}

// ---------------- fused GEMM: out = [relu]( P@Wl [+ Q@Wr] + b [+ Q resid] ) ----
// K = 128 fixed. 256 threads; thread = 8 rows x 4 cols.
template <int COLS, bool TWO, bool RELU, bool RESID>
__global__ __launch_bounds__(256) void k_gemm(const float* __restrict__ P,
                                              const float* __restrict__ Q,
                                              const float* __restrict__ Wl,
                                              const float* __restrict__ Wr,
                                              const float* __restrict__ bias,
                                              float* __restrict__ out, int n) {
    constexpr int K = 128, KC = 32, NCH = K / KC;
    constexpr int CG = COLS / 4;   // col groups of 4
    constexpr int RG = 256 / CG;   // row groups
    constexpr int RPT = 8;         // rows per thread
    constexpr int ROWS = RG * RPT; // rows per block

    __shared__ float sP[ROWS * KC];
    __shared__ float sQ[TWO ? ROWS * KC : 1];
    __shared__ float sW[KC * COLS];
    __shared__ float sW2[TWO ? KC * COLS : 1];

    const int tid = threadIdx.x;
    const int cg = tid % CG;
    const int rg = tid / CG;
    const int rowBase = blockIdx.x * ROWS;

    float acc[RPT][4];
#pragma unroll
    for (int r = 0; r < RPT; r++)
#pragma unroll
        for (int j = 0; j < 4; j++) acc[r][j] = 0.f;

    for (int ch = 0; ch < NCH; ch++) {
        const int k0 = ch * KC;
        __syncthreads();  // protect LDS reuse from previous chunk
        // stage P/Q tile: ROWS*KC floats, float4 per thread
        constexpr int LV = (ROWS * KC / 4) / 256;
#pragma unroll
        for (int v = 0; v < LV; v++) {
            int f = v * 256 + tid;
            int row = f / (KC / 4);
            int kk = (f % (KC / 4)) * 4;
            int gr = rowBase + row;
            if (gr >= n) gr = n - 1;  // clamp: stay in-bounds, values unused
            *(float4*)&sP[row * KC + kk] = *(const float4*)&P[(size_t)gr * K + k0 + kk];
            if (TWO)
                *(float4*)&sQ[row * KC + kk] = *(const float4*)&Q[(size_t)gr * K + k0 + kk];
        }
        // stage weight chunk
        constexpr int WV = (KC * COLS / 4) / 256;
#pragma unroll
        for (int v = 0; v < WV; v++) {
            int f = v * 256 + tid;
            int k = f / (COLS / 4);
            int cc = (f % (COLS / 4)) * 4;
            *(float4*)&sW[k * COLS + cc] = *(const float4*)&Wl[(size_t)(k0 + k) * COLS + cc];
            if (TWO)
                *(float4*)&sW2[k * COLS + cc] = *(const float4*)&Wr[(size_t)(k0 + k) * COLS + cc];
        }
        __syncthreads();
#pragma unroll 4
        for (int k = 0; k < KC; k++) {
            float4 wl = *(const float4*)&sW[k * COLS + cg * 4];
            float4 wr = make_float4(0.f, 0.f, 0.f, 0.f);
            if (TWO) wr = *(const float4*)&sW2[k * COLS + cg * 4];
#pragma unroll
            for (int r = 0; r < RPT; r++) {
                float a = sP[(rg * RPT + r) * KC + k];
                acc[r][0] += a * wl.x;
                acc[r][1] += a * wl.y;
                acc[r][2] += a * wl.z;
                acc[r][3] += a * wl.w;
                if (TWO) {
                    float b = sQ[(rg * RPT + r) * KC + k];
                    acc[r][0] += b * wr.x;
                    acc[r][1] += b * wr.y;
                    acc[r][2] += b * wr.z;
                    acc[r][3] += b * wr.w;
                }
            }
        }
    }
    // epilogue
    float4 bv = *(const float4*)&bias[cg * 4];
#pragma unroll
    for (int r = 0; r < RPT; r++) {
        int row = rowBase + rg * RPT + r;
        if (row < n) {
            float4 o;
            o.x = acc[r][0] + bv.x;
            o.y = acc[r][1] + bv.y;
            o.z = acc[r][2] + bv.z;
            o.w = acc[r][3] + bv.w;
            if (RESID) {
                float4 rv = *(const float4*)&Q[(size_t)row * K + cg * 4];
                o.x += rv.x; o.y += rv.y; o.z += rv.z; o.w += rv.w;
            }
            if (RELU) {
                o.x = fmaxf(o.x, 0.f); o.y = fmaxf(o.y, 0.f);
                o.z = fmaxf(o.z, 0.f); o.w = fmaxf(o.w, 0.f);
            }
            *(float4*)&out[(size_t)row * COLS + cg * 4] = o;
        }
    }
}

extern "C" void kernel_launch(void* const* d_in, const int* in_sizes, int n_in,
                              void* d_out, int out_size, void* d_ws, size_t ws_size,
                              hipStream_t stream) {
    const float* x    = (const float*)d_in[0];
    const int*   ei   = (const int*)d_in[1];   // [2,E] int32: src then dst
    const float* W1l  = (const float*)d_in[2];
    const float* b1   = (const float*)d_in[3];
    const float* W1r  = (const float*)d_in[4];
    const float* W2l  = (const float*)d_in[5];
    const float* b2   = (const float*)d_in[6];
    const float* W2r  = (const float*)d_in[7];
    const float* Wlin = (const float*)d_in[8];
    const float* blin = (const float*)d_in[9];
    float* out = (float*)d_out;

    const int N = NND, E = NED;
    const int* src = ei;
    const int* dst = ei + E;

    // workspace layout (16B-aligned chunks)
    char* w = (char*)d_ws;
    int*   deg    = (int*)w;                 w += (size_t)N * 4;      // 400000
    int*   cursor = (int*)w;                 w += (size_t)N * 4;      // contiguous with deg -> one memset
    int*   offs   = (int*)w;                 w += (size_t)(N + 4) * 4;
    float* dinv   = (float*)w;               w += (size_t)N * 4;
    int*   csr    = (int*)w;                 w += (size_t)E * 4;
    float* agg    = (float*)w;               w += (size_t)N * FIN * 4;
    float* h      = (float*)w;               w += (size_t)N * FIN * 4;

    hipMemsetAsync(deg, 0, (size_t)2 * N * 4, stream);  // deg + cursor

    k_deg<<<E / 256, 256, 0, stream>>>(dst, deg, E);
    k_scan<<<1, 1024, 0, stream>>>(deg, offs, dinv, N);
    k_csr<<<E / 256, 256, 0, stream>>>(src, dst, offs, cursor, csr, E);

    // layer 1: agg = mean(x[neigh]); h = relu(agg@W1l + x@W1r + b1)
    k_agg<<<(N + 3) / 4, 256, 0, stream>>>(x, offs, csr, dinv, agg, N);
    k_gemm<128, true, true, false><<<(N + 63) / 64, 256, 0, stream>>>(agg, x, W1l, W1r, b1, h, N);

    // layer 2: agg = mean(h[neigh]); h = relu(h + agg@W2l + h@W2r + b2)  (in place)
    k_agg<<<(N + 3) / 4, 256, 0, stream>>>(h, offs, csr, dinv, agg, N);
    k_gemm<128, true, true, true><<<(N + 63) / 64, 256, 0, stream>>>(agg, h, W2l, W2r, b2, h, N);

    // head: out = h@Wlin + blin
    k_gemm<64, false, false, false><<<(N + 127) / 128, 256, 0, stream>>>(h, h, Wlin, Wlin, blin, out, N);
}

// Round 2
// 773.335 us; speedup vs baseline: 1.2673x; 1.2673x over previous
//
#include <hip/hip_runtime.h>
#include <hip/hip_bf16.h>
#include <cstdint>

#define NND 100000
#define NED 1600000
#define FIN 128
#define FOUT 64

// ---------------- degree count ----------------
__global__ __launch_bounds__(256) void k_deg(const int* __restrict__ dst,
                                             int* __restrict__ deg, int e) {
    int i = blockIdx.x * 256 + threadIdx.x;
    if (i < e) atomicAdd(&deg[dst[i]], 1);
}

// ---------------- hierarchical exclusive scan ----------------
// phase 1: per-block (1024-elem chunk) sums
__global__ __launch_bounds__(1024) void k_scan1(const int* __restrict__ deg,
                                                int* __restrict__ psum, int n) {
    __shared__ int red[1024];
    int tid = threadIdx.x;
    int i = blockIdx.x * 1024 + tid;
    red[tid] = (i < n) ? deg[i] : 0;
    __syncthreads();
#pragma unroll
    for (int off = 512; off > 0; off >>= 1) {
        if (tid < off) red[tid] += red[tid + off];
        __syncthreads();
    }
    if (tid == 0) psum[blockIdx.x] = red[0];
}

// phase 2: exclusive scan of block sums (nb <= 128), single block
__global__ __launch_bounds__(128) void k_scan2(int* __restrict__ psum, int nb) {
    int tid = threadIdx.x;
    int d = (tid < nb) ? psum[tid] : 0;
    int v = d;
#pragma unroll
    for (int off = 1; off < 64; off <<= 1) {
        int u = __shfl_up(v, off, 64);
        if ((tid & 63) >= off) v += u;
    }
    __shared__ int ws[2];
    if ((tid & 63) == 63) ws[tid >> 6] = v;
    __syncthreads();
    int base = (tid >= 64) ? ws[0] : 0;
    if (tid < nb) psum[tid] = base + v - d;  // exclusive prefix
}

// phase 3: block-local scan + block offset -> offs, dinv
__global__ __launch_bounds__(1024) void k_scan3(const int* __restrict__ deg,
                                                const int* __restrict__ psum,
                                                int* __restrict__ offs,
                                                float* __restrict__ dinv,
                                                int n, int e) {
    int tid = threadIdx.x;
    int i = blockIdx.x * 1024 + tid;
    int d = (i < n) ? deg[i] : 0;
    int v = d;  // inclusive wave scan
#pragma unroll
    for (int off = 1; off < 64; off <<= 1) {
        int u = __shfl_up(v, off, 64);
        if ((tid & 63) >= off) v += u;
    }
    __shared__ int wsum[16];
    int wid = tid >> 6;
    if ((tid & 63) == 63) wsum[wid] = v;
    __syncthreads();
    if (tid < 16) {
        int w = wsum[tid];
#pragma unroll
        for (int off = 1; off < 16; off <<= 1) {
            int u = __shfl_up(w, off, 64);
            if (tid >= off) w += u;
        }
        wsum[tid] = w;  // inclusive wave-sum prefix
    }
    __syncthreads();
    int base = psum[blockIdx.x] + (wid ? wsum[wid - 1] : 0);
    if (i < n) {
        offs[i] = base + v - d;  // exclusive
        dinv[i] = 1.0f / fmaxf((float)d, 1.0f);
    }
    if (i == 0) offs[n] = e;  // total degree == E, a known constant
}

// ---------------- CSR fill (counting sort by dst) ----------------
__global__ __launch_bounds__(256) void k_csr(const int* __restrict__ src,
                                             const int* __restrict__ dst,
                                             const int* __restrict__ offs,
                                             int* __restrict__ cursor,
                                             int* __restrict__ csr, int e) {
    int i = blockIdx.x * 256 + threadIdx.x;
    if (i < e) {
        int d = dst[i];
        int pos = offs[d] + atomicAdd(&cursor[d], 1);
        csr[pos] = src[i];
    }
}

// ---------------- mean-aggregate: one wave per node ----------------
__global__ __launch_bounds__(256) void k_agg(const float* __restrict__ feat,
                                             const int* __restrict__ offs,
                                             const int* __restrict__ csr,
                                             const float* __restrict__ dinv,
                                             float* __restrict__ out, int n) {
    int node = blockIdx.x * 4 + (threadIdx.x >> 6);
    if (node >= n) return;
    int lane = threadIdx.x & 63;
    int beg = offs[node], end = offs[node + 1];
    const float2* f2 = (const float2*)feat;
    float2 acc = make_float2(0.f, 0.f);
    int i = beg;
    for (; i + 1 < end; i += 2) {
        int s0 = csr[i], s1 = csr[i + 1];
        float2 v0 = f2[(size_t)s0 * 64 + lane];
        float2 v1 = f2[(size_t)s1 * 64 + lane];
        acc.x += v0.x + v1.x;
        acc.y += v0.y + v1.y;
    }
    if (i < end) {
        int s0 = csr[i];
        float2 v0 = f2[(size_t)s0 * 64 + lane];
        acc.x += v0.x;
        acc.y += v0.y;
    }
    float di = dinv[node];
    ((float2*)out)[(size_t)node * 64 + lane] = make_float2(acc.x * di, acc.y * di);
}

// ---------------- fused GEMM: out = [relu]( P@Wl [+ Q@Wr] + b [+ Q resid] ) ----
// K = 128 fixed. 256 threads; thread = 8 rows x 4 cols.
template <int COLS, bool TWO, bool RELU, bool RESID>
__global__ __launch_bounds__(256) void k_gemm(const float* __restrict__ P,
                                              const float* __restrict__ Q,
                                              const float* __restrict__ Wl,
                                              const float* __restrict__ Wr,
                                              const float* __restrict__ bias,
                                              float* __restrict__ out, int n) {
    constexpr int K = 128, KC = 32, NCH = K / KC;
    constexpr int CG = COLS / 4;   // col groups of 4
    constexpr int RG = 256 / CG;   // row groups
    constexpr int RPT = 8;         // rows per thread
    constexpr int ROWS = RG * RPT; // rows per block

    __shared__ float sP[ROWS * KC];
    __shared__ float sQ[TWO ? ROWS * KC : 1];
    __shared__ float sW[KC * COLS];
    __shared__ float sW2[TWO ? KC * COLS : 1];

    const int tid = threadIdx.x;
    const int cg = tid % CG;
    const int rg = tid / CG;
    const int rowBase = blockIdx.x * ROWS;

    float acc[RPT][4];
#pragma unroll
    for (int r = 0; r < RPT; r++)
#pragma unroll
        for (int j = 0; j < 4; j++) acc[r][j] = 0.f;

    for (int ch = 0; ch < NCH; ch++) {
        const int k0 = ch * KC;
        __syncthreads();  // protect LDS reuse from previous chunk
        constexpr int LV = (ROWS * KC / 4) / 256;
#pragma unroll
        for (int v = 0; v < LV; v++) {
            int f = v * 256 + tid;
            int row = f / (KC / 4);
            int kk = (f % (KC / 4)) * 4;
            int gr = rowBase + row;
            if (gr >= n) gr = n - 1;  // clamp: stay in-bounds, values unused
            *(float4*)&sP[row * KC + kk] = *(const float4*)&P[(size_t)gr * K + k0 + kk];
            if (TWO)
                *(float4*)&sQ[row * KC + kk] = *(const float4*)&Q[(size_t)gr * K + k0 + kk];
        }
        constexpr int WV = (KC * COLS / 4) / 256;
#pragma unroll
        for (int v = 0; v < WV; v++) {
            int f = v * 256 + tid;
            int k = f / (COLS / 4);
            int cc = (f % (COLS / 4)) * 4;
            *(float4*)&sW[k * COLS + cc] = *(const float4*)&Wl[(size_t)(k0 + k) * COLS + cc];
            if (TWO)
                *(float4*)&sW2[k * COLS + cc] = *(const float4*)&Wr[(size_t)(k0 + k) * COLS + cc];
        }
        __syncthreads();
#pragma unroll 4
        for (int k = 0; k < KC; k++) {
            float4 wl = *(const float4*)&sW[k * COLS + cg * 4];
            float4 wr = make_float4(0.f, 0.f, 0.f, 0.f);
            if (TWO) wr = *(const float4*)&sW2[k * COLS + cg * 4];
#pragma unroll
            for (int r = 0; r < RPT; r++) {
                float a = sP[(rg * RPT + r) * KC + k];
                acc[r][0] += a * wl.x;
                acc[r][1] += a * wl.y;
                acc[r][2] += a * wl.z;
                acc[r][3] += a * wl.w;
                if (TWO) {
                    float b = sQ[(rg * RPT + r) * KC + k];
                    acc[r][0] += b * wr.x;
                    acc[r][1] += b * wr.y;
                    acc[r][2] += b * wr.z;
                    acc[r][3] += b * wr.w;
                }
            }
        }
    }
    // epilogue
    float4 bv = *(const float4*)&bias[cg * 4];
#pragma unroll
    for (int r = 0; r < RPT; r++) {
        int row = rowBase + rg * RPT + r;
        if (row < n) {
            float4 o;
            o.x = acc[r][0] + bv.x;
            o.y = acc[r][1] + bv.y;
            o.z = acc[r][2] + bv.z;
            o.w = acc[r][3] + bv.w;
            if (RESID) {
                float4 rv = *(const float4*)&Q[(size_t)row * K + cg * 4];
                o.x += rv.x; o.y += rv.y; o.z += rv.z; o.w += rv.w;
            }
            if (RELU) {
                o.x = fmaxf(o.x, 0.f); o.y = fmaxf(o.y, 0.f);
                o.z = fmaxf(o.z, 0.f); o.w = fmaxf(o.w, 0.f);
            }
            *(float4*)&out[(size_t)row * COLS + cg * 4] = o;
        }
    }
}

extern "C" void kernel_launch(void* const* d_in, const int* in_sizes, int n_in,
                              void* d_out, int out_size, void* d_ws, size_t ws_size,
                              hipStream_t stream) {
    const float* x    = (const float*)d_in[0];
    const int*   ei   = (const int*)d_in[1];   // [2,E] int32: src then dst
    const float* W1l  = (const float*)d_in[2];
    const float* b1   = (const float*)d_in[3];
    const float* W1r  = (const float*)d_in[4];
    const float* W2l  = (const float*)d_in[5];
    const float* b2   = (const float*)d_in[6];
    const float* W2r  = (const float*)d_in[7];
    const float* Wlin = (const float*)d_in[8];
    const float* blin = (const float*)d_in[9];
    float* out = (float*)d_out;

    const int N = NND, E = NED;
    const int* src = ei;
    const int* dst = ei + E;
    const int NB = (N + 1023) / 1024;  // 98 scan blocks

    // workspace layout (16B-aligned chunks)
    char* w = (char*)d_ws;
    int*   deg    = (int*)w;                 w += (size_t)N * 4;
    int*   cursor = (int*)w;                 w += (size_t)N * 4;      // contiguous with deg -> one memset
    int*   offs   = (int*)w;                 w += (size_t)(N + 4) * 4;
    float* dinv   = (float*)w;               w += (size_t)N * 4;
    int*   psum   = (int*)w;                 w += (size_t)((NB + 3) & ~3) * 4;
    int*   csr    = (int*)w;                 w += (size_t)E * 4;
    float* agg    = (float*)w;               w += (size_t)N * FIN * 4;
    float* h      = (float*)w;               w += (size_t)N * FIN * 4;

    hipMemsetAsync(deg, 0, (size_t)2 * N * 4, stream);  // deg + cursor

    k_deg<<<E / 256, 256, 0, stream>>>(dst, deg, E);
    k_scan1<<<NB, 1024, 0, stream>>>(deg, psum, N);
    k_scan2<<<1, 128, 0, stream>>>(psum, NB);
    k_scan3<<<NB, 1024, 0, stream>>>(deg, psum, offs, dinv, N, E);
    k_csr<<<E / 256, 256, 0, stream>>>(src, dst, offs, cursor, csr, E);

    // layer 1: agg = mean(x[neigh]); h = relu(agg@W1l + x@W1r + b1)
    k_agg<<<(N + 3) / 4, 256, 0, stream>>>(x, offs, csr, dinv, agg, N);
    k_gemm<128, true, true, false><<<(N + 63) / 64, 256, 0, stream>>>(agg, x, W1l, W1r, b1, h, N);

    // layer 2: agg = mean(h[neigh]); h = relu(h + agg@W2l + h@W2r + b2)  (in place)
    k_agg<<<(N + 3) / 4, 256, 0, stream>>>(h, offs, csr, dinv, agg, N);
    k_gemm<128, true, true, true><<<(N + 63) / 64, 256, 0, stream>>>(agg, h, W2l, W2r, b2, h, N);

    // head: out = h@Wlin + blin
    k_gemm<64, false, false, false><<<(N + 127) / 128, 256, 0, stream>>>(h, h, Wlin, Wlin, blin, out, N);
}

// Round 3
// 566.732 us; speedup vs baseline: 1.7293x; 1.3646x over previous
//
#include <hip/hip_runtime.h>
#include <hip/hip_bf16.h>
#include <cstdint>

#define NND 100000
#define NED 1600000
#define FIN 128
#define FOUT 64

typedef __bf16 bf16x8 __attribute__((ext_vector_type(8)));
typedef float f32x4 __attribute__((ext_vector_type(4)));

static __device__ inline unsigned short f2bf(float f) {
    unsigned int u = __builtin_bit_cast(unsigned int, f);
    unsigned int r = (u + 0x7fffu + ((u >> 16) & 1u)) >> 16;  // RNE
    return (unsigned short)r;
}
static __device__ inline float bflo(unsigned int v) {  // low ushort -> float
    return __builtin_bit_cast(float, v << 16);
}
static __device__ inline float bfhi(unsigned int v) {  // high ushort -> float
    return __builtin_bit_cast(float, v & 0xffff0000u);
}
static __device__ inline float bf1(unsigned short u) {
    return __builtin_bit_cast(float, (unsigned int)u << 16);
}

// ---------------- degree count ----------------
__global__ __launch_bounds__(256) void k_deg(const int* __restrict__ dst,
                                             int* __restrict__ deg, int e) {
    int i = blockIdx.x * 256 + threadIdx.x;
    if (i < e) atomicAdd(&deg[dst[i]], 1);
}

// ---------------- hierarchical exclusive scan ----------------
__global__ __launch_bounds__(1024) void k_scan1(const int* __restrict__ deg,
                                                int* __restrict__ psum, int n) {
    __shared__ int red[1024];
    int tid = threadIdx.x;
    int i = blockIdx.x * 1024 + tid;
    red[tid] = (i < n) ? deg[i] : 0;
    __syncthreads();
#pragma unroll
    for (int off = 512; off > 0; off >>= 1) {
        if (tid < off) red[tid] += red[tid + off];
        __syncthreads();
    }
    if (tid == 0) psum[blockIdx.x] = red[0];
}

__global__ __launch_bounds__(128) void k_scan2(int* __restrict__ psum, int nb) {
    int tid = threadIdx.x;
    int d = (tid < nb) ? psum[tid] : 0;
    int v = d;
#pragma unroll
    for (int off = 1; off < 64; off <<= 1) {
        int u = __shfl_up(v, off, 64);
        if ((tid & 63) >= off) v += u;
    }
    __shared__ int ws[2];
    if ((tid & 63) == 63) ws[tid >> 6] = v;
    __syncthreads();
    int base = (tid >= 64) ? ws[0] : 0;
    if (tid < nb) psum[tid] = base + v - d;
}

__global__ __launch_bounds__(1024) void k_scan3(const int* __restrict__ deg,
                                                const int* __restrict__ psum,
                                                int* __restrict__ offs,
                                                float* __restrict__ dinv,
                                                int n, int e) {
    int tid = threadIdx.x;
    int i = blockIdx.x * 1024 + tid;
    int d = (i < n) ? deg[i] : 0;
    int v = d;
#pragma unroll
    for (int off = 1; off < 64; off <<= 1) {
        int u = __shfl_up(v, off, 64);
        if ((tid & 63) >= off) v += u;
    }
    __shared__ int wsum[16];
    int wid = tid >> 6;
    if ((tid & 63) == 63) wsum[wid] = v;
    __syncthreads();
    if (tid < 16) {
        int w = wsum[tid];
#pragma unroll
        for (int off = 1; off < 16; off <<= 1) {
            int u = __shfl_up(w, off, 64);
            if (tid >= off) w += u;
        }
        wsum[tid] = w;
    }
    __syncthreads();
    int base = psum[blockIdx.x] + (wid ? wsum[wid - 1] : 0);
    if (i < n) {
        offs[i] = base + v - d;
        dinv[i] = 1.0f / fmaxf((float)d, 1.0f);
    }
    if (i == 0) offs[n] = e;
}

// ---------------- CSR fill ----------------
__global__ __launch_bounds__(256) void k_csr(const int* __restrict__ src,
                                             const int* __restrict__ dst,
                                             const int* __restrict__ offs,
                                             int* __restrict__ cursor,
                                             int* __restrict__ csr, int e) {
    int i = blockIdx.x * 256 + threadIdx.x;
    if (i < e) {
        int d = dst[i];
        int pos = offs[d] + atomicAdd(&cursor[d], 1);
        csr[pos] = src[i];
    }
}

// ---------------- cast x (fp32) -> bf16 ----------------
__global__ __launch_bounds__(256) void k_castx(const float* __restrict__ x,
                                               unsigned int* __restrict__ xb,
                                               int total2) {  // total2 = N*64
    int i = blockIdx.x * 256 + threadIdx.x;
    if (i < total2) {
        float2 v = ((const float2*)x)[i];
        xb[i] = (unsigned int)f2bf(v.x) | ((unsigned int)f2bf(v.y) << 16);
    }
}

// ---------------- weight pack into MFMA B-fragment order ----------------
// B frag (16x16x32): lane holds B[k = (lane>>4)*8 + j][n = lane&15], j=0..7
// packed[((c*NTtot + nt)*64 + lane)*8 + j]
static __device__ inline void pack_one(const float* __restrict__ W,
                                       unsigned short* __restrict__ out,
                                       int NTtot, int c_local, int nt,
                                       int chunkOff, int ncols, int lane) {
    int k = c_local * 32 + (lane >> 4) * 8;
    int n = nt * 16 + (lane & 15);
    unsigned short t[8];
#pragma unroll
    for (int j = 0; j < 8; j++) t[j] = f2bf(W[(size_t)(k + j) * ncols + n]);
    uint4 u;
    u.x = t[0] | ((unsigned)t[1] << 16);
    u.y = t[2] | ((unsigned)t[3] << 16);
    u.z = t[4] | ((unsigned)t[5] << 16);
    u.w = t[6] | ((unsigned)t[7] << 16);
    *(uint4*)&out[((size_t)((c_local + chunkOff) * NTtot + nt) * 64 + lane) * 8] = u;
}

__global__ __launch_bounds__(64) void k_packAll(const float* W1l, const float* W1r,
                                                const float* W2l, const float* W2r,
                                                const float* Wlin,
                                                unsigned short* p1, unsigned short* p2,
                                                unsigned short* ph) {
    int b = blockIdx.x, lane = threadIdx.x;
    if (b < 32)       pack_one(W1l, p1, 8, b >> 3, b & 7, 0, 128, lane);
    else if (b < 64)  { b -= 32; pack_one(W1r, p1, 8, b >> 3, b & 7, 4, 128, lane); }
    else if (b < 96)  { b -= 64; pack_one(W2l, p2, 8, b >> 3, b & 7, 0, 128, lane); }
    else if (b < 128) { b -= 96; pack_one(W2r, p2, 8, b >> 3, b & 7, 4, 128, lane); }
    else              { b -= 128; pack_one(Wlin, ph, 4, b >> 2, b & 3, 0, 64, lane); }
}

// ---------------- mean-aggregate (bf16 features): one wave per node ----------
__global__ __launch_bounds__(256) void k_aggb(const unsigned int* __restrict__ feat,
                                              const int* __restrict__ offs,
                                              const int* __restrict__ csr,
                                              const float* __restrict__ dinv,
                                              unsigned int* __restrict__ out, int n) {
    int node = blockIdx.x * 4 + (threadIdx.x >> 6);
    if (node >= n) return;
    int lane = threadIdx.x & 63;
    int beg = offs[node], end = offs[node + 1];
    float ax = 0.f, ay = 0.f;
    int i = beg;
    for (; i + 1 < end; i += 2) {
        int s0 = csr[i], s1 = csr[i + 1];
        unsigned int v0 = feat[(size_t)s0 * 64 + lane];
        unsigned int v1 = feat[(size_t)s1 * 64 + lane];
        ax += bflo(v0) + bflo(v1);
        ay += bfhi(v0) + bfhi(v1);
    }
    if (i < end) {
        unsigned int v0 = feat[(size_t)csr[i] * 64 + lane];
        ax += bflo(v0);
        ay += bfhi(v0);
    }
    float di = dinv[node];
    out[(size_t)node * 64 + lane] =
        (unsigned int)f2bf(ax * di) | ((unsigned int)f2bf(ay * di) << 16);
}

// ---------------- MFMA GEMM ----------------
// out[n, NT*16] = [relu]( [P|Q](K) @ Wpacked + bias [+ resid] )
// 256 thr = 4 waves; wave owns 16 rows x NT*16 cols. No LDS: A read once,
// B packed + L2-resident.
template <int NT, int KCH, bool TWO, bool RELU, bool RESID, bool OUTBF>
__global__ __launch_bounds__(256) void k_mfma(const unsigned short* __restrict__ P,
                                              const unsigned short* __restrict__ Q,
                                              const unsigned short* __restrict__ Wp,
                                              const float* __restrict__ bias,
                                              const unsigned short* __restrict__ resid,
                                              void* __restrict__ outv, int n) {
    const int lane = threadIdx.x & 63;
    const int wave = threadIdx.x >> 6;
    const int quad = lane >> 4;
    const int row0 = blockIdx.x * 64 + wave * 16;
    int rowA = row0 + (lane & 15);
    if (rowA >= n) rowA = n - 1;  // clamp; junk rows masked in epilogue

    f32x4 acc[NT];
#pragma unroll
    for (int t = 0; t < NT; t++) acc[t] = (f32x4){0.f, 0.f, 0.f, 0.f};

#pragma unroll
    for (int c = 0; c < KCH; c++) {
        const unsigned short* Abase = (TWO && c >= KCH / 2) ? Q : P;
        const int kk = (TWO ? (c & (KCH / 2 - 1)) : c) * 32 + quad * 8;
        bf16x8 a = *(const bf16x8*)&Abase[(size_t)rowA * 128 + kk];
#pragma unroll
        for (int t = 0; t < NT; t++) {
            bf16x8 b = *(const bf16x8*)&Wp[(size_t)((c * NT + t) * 64 + lane) * 8];
            acc[t] = __builtin_amdgcn_mfma_f32_16x16x32_bf16(a, b, acc[t], 0, 0, 0);
        }
    }

    const int col = lane & 15;
#pragma unroll
    for (int t = 0; t < NT; t++) {
        float bv = bias[t * 16 + col];
#pragma unroll
        for (int r = 0; r < 4; r++) {
            int row = row0 + quad * 4 + r;
            if (row < n) {
                float v = acc[t][r] + bv;
                if (RESID) v += bf1(resid[(size_t)row * 128 + t * 16 + col]);
                if (RELU) v = fmaxf(v, 0.f);
                if (OUTBF)
                    ((unsigned short*)outv)[(size_t)row * (NT * 16) + t * 16 + col] = f2bf(v);
                else
                    ((float*)outv)[(size_t)row * (NT * 16) + t * 16 + col] = v;
            }
        }
    }
}

extern "C" void kernel_launch(void* const* d_in, const int* in_sizes, int n_in,
                              void* d_out, int out_size, void* d_ws, size_t ws_size,
                              hipStream_t stream) {
    const float* x    = (const float*)d_in[0];
    const int*   ei   = (const int*)d_in[1];
    const float* W1l  = (const float*)d_in[2];
    const float* b1   = (const float*)d_in[3];
    const float* W1r  = (const float*)d_in[4];
    const float* W2l  = (const float*)d_in[5];
    const float* b2   = (const float*)d_in[6];
    const float* W2r  = (const float*)d_in[7];
    const float* Wlin = (const float*)d_in[8];
    const float* blin = (const float*)d_in[9];
    float* out = (float*)d_out;

    const int N = NND, E = NED;
    const int* src = ei;
    const int* dst = ei + E;
    const int NB = (N + 1023) / 1024;

    // workspace layout
    char* w = (char*)d_ws;
    int*   deg    = (int*)w;               w += (size_t)N * 4;
    int*   cursor = (int*)w;               w += (size_t)N * 4;   // contiguous with deg
    int*   offs   = (int*)w;               w += (size_t)(N + 4) * 4;
    float* dinv   = (float*)w;             w += (size_t)N * 4;
    int*   psum   = (int*)w;               w += (size_t)((NB + 3) & ~3) * 4;
    int*   csr    = (int*)w;               w += (size_t)E * 4;
    unsigned short* p1  = (unsigned short*)w;  w += 256 * 128 * 2;  // fused [W1l;W1r]
    unsigned short* p2  = (unsigned short*)w;  w += 256 * 128 * 2;
    unsigned short* ph  = (unsigned short*)w;  w += 128 * 64 * 2;
    unsigned short* xb  = (unsigned short*)w;  w += (size_t)N * 128 * 2;  // bf16 x
    unsigned short* agg = (unsigned short*)w;  w += (size_t)N * 128 * 2;
    unsigned short* h1  = (unsigned short*)w;  w += (size_t)N * 128 * 2;
    unsigned short* h2  = (unsigned short*)w;  w += (size_t)N * 128 * 2;

    hipMemsetAsync(deg, 0, (size_t)2 * N * 4, stream);

    k_deg<<<E / 256, 256, 0, stream>>>(dst, deg, E);
    k_scan1<<<NB, 1024, 0, stream>>>(deg, psum, N);
    k_scan2<<<1, 128, 0, stream>>>(psum, NB);
    k_scan3<<<NB, 1024, 0, stream>>>(deg, psum, offs, dinv, N, E);
    k_csr<<<E / 256, 256, 0, stream>>>(src, dst, offs, cursor, csr, E);
    k_castx<<<(N * 64 + 255) / 256, 256, 0, stream>>>(x, (unsigned int*)xb, N * 64);
    k_packAll<<<144, 64, 0, stream>>>(W1l, W1r, W2l, W2r, Wlin, p1, p2, ph);

    // layer 1: agg = mean(xb[neigh]); h1 = relu([agg|xb] @ [W1l;W1r] + b1)
    k_aggb<<<(N + 3) / 4, 256, 0, stream>>>((const unsigned int*)xb, offs, csr, dinv,
                                            (unsigned int*)agg, N);
    k_mfma<8, 8, true, true, false, true><<<(N + 63) / 64, 256, 0, stream>>>(
        agg, xb, p1, b1, nullptr, h1, N);

    // layer 2: agg = mean(h1[neigh]); h2 = relu(h1 + [agg|h1] @ [W2l;W2r] + b2)
    k_aggb<<<(N + 3) / 4, 256, 0, stream>>>((const unsigned int*)h1, offs, csr, dinv,
                                            (unsigned int*)agg, N);
    k_mfma<8, 8, true, true, true, true><<<(N + 63) / 64, 256, 0, stream>>>(
        agg, h1, p2, b2, h1, h2, N);

    // head: out = h2 @ Wlin + blin (fp32 out)
    k_mfma<4, 4, false, false, false, false><<<(N + 63) / 64, 256, 0, stream>>>(
        h2, nullptr, ph, blin, nullptr, out, N);
}

// Round 4
// 508.464 us; speedup vs baseline: 1.9274x; 1.1146x over previous
//
#include <hip/hip_runtime.h>
#include <hip/hip_bf16.h>
#include <cstdint>

#define NND 100000
#define NED 1600000
#define FIN 128
#define FOUT 64

typedef __bf16 bf16x8 __attribute__((ext_vector_type(8)));
typedef float f32x4 __attribute__((ext_vector_type(4)));

static __device__ inline unsigned short f2bf(float f) {
    unsigned int u = __builtin_bit_cast(unsigned int, f);
    unsigned int r = (u + 0x7fffu + ((u >> 16) & 1u)) >> 16;  // RNE
    return (unsigned short)r;
}
static __device__ inline float bflo(unsigned int v) {
    return __builtin_bit_cast(float, v << 16);
}
static __device__ inline float bfhi(unsigned int v) {
    return __builtin_bit_cast(float, v & 0xffff0000u);
}
static __device__ inline float bf1(unsigned short u) {
    return __builtin_bit_cast(float, (unsigned int)u << 16);
}

// ---------------- degree count + x cast (fused, independent ranges) --------
__global__ __launch_bounds__(256) void k_deg_cast(const int* __restrict__ dst,
                                                  int* __restrict__ deg, int e,
                                                  const float* __restrict__ x,
                                                  unsigned int* __restrict__ xb,
                                                  int total2) {
    int i = blockIdx.x * 256 + threadIdx.x;
    if (i < e) atomicAdd(&deg[dst[i]], 1);
    if (i < total2) {
        float2 v = ((const float2*)x)[i];
        xb[i] = (unsigned int)f2bf(v.x) | ((unsigned int)f2bf(v.y) << 16);
    }
}

// ---------------- hierarchical exclusive scan ----------------
__global__ __launch_bounds__(1024) void k_scan1(const int* __restrict__ deg,
                                                int* __restrict__ psum, int n) {
    __shared__ int red[1024];
    int tid = threadIdx.x;
    int i = blockIdx.x * 1024 + tid;
    red[tid] = (i < n) ? deg[i] : 0;
    __syncthreads();
#pragma unroll
    for (int off = 512; off > 0; off >>= 1) {
        if (tid < off) red[tid] += red[tid + off];
        __syncthreads();
    }
    if (tid == 0) psum[blockIdx.x] = red[0];
}

__global__ __launch_bounds__(128) void k_scan2(int* __restrict__ psum, int nb) {
    int tid = threadIdx.x;
    int d = (tid < nb) ? psum[tid] : 0;
    int v = d;
#pragma unroll
    for (int off = 1; off < 64; off <<= 1) {
        int u = __shfl_up(v, off, 64);
        if ((tid & 63) >= off) v += u;
    }
    __shared__ int ws[2];
    if ((tid & 63) == 63) ws[tid >> 6] = v;
    __syncthreads();
    int base = (tid >= 64) ? ws[0] : 0;
    if (tid < nb) psum[tid] = base + v - d;
}

__global__ __launch_bounds__(1024) void k_scan3(const int* __restrict__ deg,
                                                const int* __restrict__ psum,
                                                int* __restrict__ offs,
                                                float* __restrict__ dinv,
                                                int n, int e) {
    int tid = threadIdx.x;
    int i = blockIdx.x * 1024 + tid;
    int d = (i < n) ? deg[i] : 0;
    int v = d;
#pragma unroll
    for (int off = 1; off < 64; off <<= 1) {
        int u = __shfl_up(v, off, 64);
        if ((tid & 63) >= off) v += u;
    }
    __shared__ int wsum[16];
    int wid = tid >> 6;
    if ((tid & 63) == 63) wsum[wid] = v;
    __syncthreads();
    if (tid < 16) {
        int w = wsum[tid];
#pragma unroll
        for (int off = 1; off < 16; off <<= 1) {
            int u = __shfl_up(w, off, 64);
            if (tid >= off) w += u;
        }
        wsum[tid] = w;
    }
    __syncthreads();
    int base = psum[blockIdx.x] + (wid ? wsum[wid - 1] : 0);
    if (i < n) {
        offs[i] = base + v - d;
        dinv[i] = 1.0f / fmaxf((float)d, 1.0f);
    }
    if (i == 0) offs[n] = e;
}

// ---------------- CSR fill ----------------
__global__ __launch_bounds__(256) void k_csr(const int* __restrict__ src,
                                             const int* __restrict__ dst,
                                             const int* __restrict__ offs,
                                             int* __restrict__ cursor,
                                             int* __restrict__ csr, int e) {
    int i = blockIdx.x * 256 + threadIdx.x;
    if (i < e) {
        int d = dst[i];
        int pos = offs[d] + atomicAdd(&cursor[d], 1);
        csr[pos] = src[i];
    }
}

// ---------------- weight pack into MFMA B-fragment order ----------------
static __device__ inline void pack_one(const float* __restrict__ W,
                                       unsigned short* __restrict__ out,
                                       int NTtot, int c_local, int nt,
                                       int chunkOff, int ncols, int lane) {
    int k = c_local * 32 + (lane >> 4) * 8;
    int n = nt * 16 + (lane & 15);
    unsigned short t[8];
#pragma unroll
    for (int j = 0; j < 8; j++) t[j] = f2bf(W[(size_t)(k + j) * ncols + n]);
    uint4 u;
    u.x = t[0] | ((unsigned)t[1] << 16);
    u.y = t[2] | ((unsigned)t[3] << 16);
    u.z = t[4] | ((unsigned)t[5] << 16);
    u.w = t[6] | ((unsigned)t[7] << 16);
    *(uint4*)&out[((size_t)((c_local + chunkOff) * NTtot + nt) * 64 + lane) * 8] = u;
}

__global__ __launch_bounds__(64) void k_packAll(const float* W1l, const float* W1r,
                                                const float* W2l, const float* W2r,
                                                const float* Wlin,
                                                unsigned short* p1, unsigned short* p2,
                                                unsigned short* ph) {
    int b = blockIdx.x, lane = threadIdx.x;
    if (b < 32)       pack_one(W1l, p1, 8, b >> 3, b & 7, 0, 128, lane);
    else if (b < 64)  { b -= 32; pack_one(W1r, p1, 8, b >> 3, b & 7, 4, 128, lane); }
    else if (b < 96)  { b -= 64; pack_one(W2l, p2, 8, b >> 3, b & 7, 0, 128, lane); }
    else if (b < 128) { b -= 96; pack_one(W2r, p2, 8, b >> 3, b & 7, 4, 128, lane); }
    else              { b -= 128; pack_one(Wlin, ph, 4, b >> 2, b & 3, 0, 64, lane); }
}

// ---------------- mean-aggregate (bf16): wave per node, 4 edges/issue -------
// lane = (grp 0..3, ch 0..15): lane loads uint4 (16B) of edge (i+grp)'s row
// chunk ch. One dwordx4 gathers 4 full edge-rows (1KB). 2-deep unroll.
__global__ __launch_bounds__(256) void k_aggb(const uint4* __restrict__ feat4,
                                              const int* __restrict__ offs,
                                              const int* __restrict__ csr,
                                              const float* __restrict__ dinv,
                                              uint4* __restrict__ out4, int n) {
    int node = blockIdx.x * 4 + (threadIdx.x >> 6);
    if (node >= n) return;
    int lane = threadIdx.x & 63;
    int grp = lane >> 4;
    int ch = lane & 15;
    int beg = offs[node], end = offs[node + 1];

    float acc[8];
#pragma unroll
    for (int j = 0; j < 8; j++) acc[j] = 0.f;

    for (int i = beg; i < end; i += 8) {
        int e0 = i + grp;
        int e1 = i + 4 + grp;
        bool p0 = e0 < end, p1 = e1 < end;
        int s0 = p0 ? csr[e0] : 0;
        int s1 = p1 ? csr[e1] : 0;
        uint4 v0 = feat4[(size_t)s0 * 16 + ch];
        uint4 v1 = feat4[(size_t)s1 * 16 + ch];
        if (p0) {
            acc[0] += bflo(v0.x); acc[1] += bfhi(v0.x);
            acc[2] += bflo(v0.y); acc[3] += bfhi(v0.y);
            acc[4] += bflo(v0.z); acc[5] += bfhi(v0.z);
            acc[6] += bflo(v0.w); acc[7] += bfhi(v0.w);
        }
        if (p1) {
            acc[0] += bflo(v1.x); acc[1] += bfhi(v1.x);
            acc[2] += bflo(v1.y); acc[3] += bfhi(v1.y);
            acc[4] += bflo(v1.z); acc[5] += bfhi(v1.z);
            acc[6] += bflo(v1.w); acc[7] += bfhi(v1.w);
        }
    }
    // combine the 4 edge-groups (same ch across lanes l, l^16, l^32)
#pragma unroll
    for (int j = 0; j < 8; j++) {
        acc[j] += __shfl_xor(acc[j], 16);
        acc[j] += __shfl_xor(acc[j], 32);
    }
    if (grp == 0) {
        float di = dinv[node];
        uint4 o;
        o.x = (unsigned)f2bf(acc[0] * di) | ((unsigned)f2bf(acc[1] * di) << 16);
        o.y = (unsigned)f2bf(acc[2] * di) | ((unsigned)f2bf(acc[3] * di) << 16);
        o.z = (unsigned)f2bf(acc[4] * di) | ((unsigned)f2bf(acc[5] * di) << 16);
        o.w = (unsigned)f2bf(acc[6] * di) | ((unsigned)f2bf(acc[7] * di) << 16);
        out4[(size_t)node * 16 + ch] = o;
    }
}

// ---------------- MFMA GEMM ----------------
template <int NT, int KCH, bool TWO, bool RELU, bool RESID, bool OUTBF>
__global__ __launch_bounds__(256) void k_mfma(const unsigned short* __restrict__ P,
                                              const unsigned short* __restrict__ Q,
                                              const unsigned short* __restrict__ Wp,
                                              const float* __restrict__ bias,
                                              const unsigned short* __restrict__ resid,
                                              void* __restrict__ outv, int n) {
    const int lane = threadIdx.x & 63;
    const int wave = threadIdx.x >> 6;
    const int quad = lane >> 4;
    const int row0 = blockIdx.x * 64 + wave * 16;
    int rowA = row0 + (lane & 15);
    if (rowA >= n) rowA = n - 1;

    f32x4 acc[NT];
#pragma unroll
    for (int t = 0; t < NT; t++) acc[t] = (f32x4){0.f, 0.f, 0.f, 0.f};

#pragma unroll
    for (int c = 0; c < KCH; c++) {
        const unsigned short* Abase = (TWO && c >= KCH / 2) ? Q : P;
        const int kk = (TWO ? (c & (KCH / 2 - 1)) : c) * 32 + quad * 8;
        bf16x8 a = *(const bf16x8*)&Abase[(size_t)rowA * 128 + kk];
#pragma unroll
        for (int t = 0; t < NT; t++) {
            bf16x8 b = *(const bf16x8*)&Wp[(size_t)((c * NT + t) * 64 + lane) * 8];
            acc[t] = __builtin_amdgcn_mfma_f32_16x16x32_bf16(a, b, acc[t], 0, 0, 0);
        }
    }

    const int col = lane & 15;
#pragma unroll
    for (int t = 0; t < NT; t++) {
        float bv = bias[t * 16 + col];
#pragma unroll
        for (int r = 0; r < 4; r++) {
            int row = row0 + quad * 4 + r;
            if (row < n) {
                float v = acc[t][r] + bv;
                if (RESID) v += bf1(resid[(size_t)row * 128 + t * 16 + col]);
                if (RELU) v = fmaxf(v, 0.f);
                if (OUTBF)
                    ((unsigned short*)outv)[(size_t)row * (NT * 16) + t * 16 + col] = f2bf(v);
                else
                    ((float*)outv)[(size_t)row * (NT * 16) + t * 16 + col] = v;
            }
        }
    }
}

extern "C" void kernel_launch(void* const* d_in, const int* in_sizes, int n_in,
                              void* d_out, int out_size, void* d_ws, size_t ws_size,
                              hipStream_t stream) {
    const float* x    = (const float*)d_in[0];
    const int*   ei   = (const int*)d_in[1];
    const float* W1l  = (const float*)d_in[2];
    const float* b1   = (const float*)d_in[3];
    const float* W1r  = (const float*)d_in[4];
    const float* W2l  = (const float*)d_in[5];
    const float* b2   = (const float*)d_in[6];
    const float* W2r  = (const float*)d_in[7];
    const float* Wlin = (const float*)d_in[8];
    const float* blin = (const float*)d_in[9];
    float* out = (float*)d_out;

    const int N = NND, E = NED;
    const int* src = ei;
    const int* dst = ei + E;
    const int NB = (N + 1023) / 1024;

    char* w = (char*)d_ws;
    int*   deg    = (int*)w;               w += (size_t)N * 4;
    int*   cursor = (int*)w;               w += (size_t)N * 4;   // contiguous with deg
    int*   offs   = (int*)w;               w += (size_t)(N + 4) * 4;
    float* dinv   = (float*)w;             w += (size_t)N * 4;
    int*   psum   = (int*)w;               w += (size_t)((NB + 3) & ~3) * 4;
    int*   csr    = (int*)w;               w += (size_t)E * 4;
    unsigned short* p1  = (unsigned short*)w;  w += 256 * 128 * 2;
    unsigned short* p2  = (unsigned short*)w;  w += 256 * 128 * 2;
    unsigned short* ph  = (unsigned short*)w;  w += 128 * 64 * 2;
    unsigned short* xb  = (unsigned short*)w;  w += (size_t)N * 128 * 2;
    unsigned short* agg = (unsigned short*)w;  w += (size_t)N * 128 * 2;
    unsigned short* h1  = (unsigned short*)w;  w += (size_t)N * 128 * 2;
    unsigned short* h2  = (unsigned short*)w;  w += (size_t)N * 128 * 2;

    hipMemsetAsync(deg, 0, (size_t)2 * N * 4, stream);

    k_deg_cast<<<(N * 64 + 255) / 256, 256, 0, stream>>>(dst, deg, E, x,
                                                         (unsigned int*)xb, N * 64);
    k_scan1<<<NB, 1024, 0, stream>>>(deg, psum, N);
    k_scan2<<<1, 128, 0, stream>>>(psum, NB);
    k_scan3<<<NB, 1024, 0, stream>>>(deg, psum, offs, dinv, N, E);
    k_csr<<<E / 256, 256, 0, stream>>>(src, dst, offs, cursor, csr, E);
    k_packAll<<<144, 64, 0, stream>>>(W1l, W1r, W2l, W2r, Wlin, p1, p2, ph);

    // layer 1
    k_aggb<<<(N + 3) / 4, 256, 0, stream>>>((const uint4*)xb, offs, csr, dinv,
                                            (uint4*)agg, N);
    k_mfma<8, 8, true, true, false, true><<<(N + 63) / 64, 256, 0, stream>>>(
        agg, xb, p1, b1, nullptr, h1, N);

    // layer 2
    k_aggb<<<(N + 3) / 4, 256, 0, stream>>>((const uint4*)h1, offs, csr, dinv,
                                            (uint4*)agg, N);
    k_mfma<8, 8, true, true, true, true><<<(N + 63) / 64, 256, 0, stream>>>(
        agg, h1, p2, b2, h1, h2, N);

    // head
    k_mfma<4, 4, false, false, false, false><<<(N + 63) / 64, 256, 0, stream>>>(
        h2, nullptr, ph, blin, nullptr, out, N);
}

// Round 5
// 470.712 us; speedup vs baseline: 2.0820x; 1.0802x over previous
//
#include <hip/hip_runtime.h>
#include <hip/hip_bf16.h>
#include <cstdint>

#define NND 100000
#define NED 1600000
#define FIN 128
#define FOUT 64

typedef __bf16 bf16x8 __attribute__((ext_vector_type(8)));
typedef float f32x4 __attribute__((ext_vector_type(4)));

static __device__ inline unsigned short f2bf(float f) {
    unsigned int u = __builtin_bit_cast(unsigned int, f);
    unsigned int r = (u + 0x7fffu + ((u >> 16) & 1u)) >> 16;  // RNE
    return (unsigned short)r;
}
static __device__ inline float bflo(unsigned int v) {
    return __builtin_bit_cast(float, v << 16);
}
static __device__ inline float bfhi(unsigned int v) {
    return __builtin_bit_cast(float, v & 0xffff0000u);
}
static __device__ inline float bf1(unsigned short u) {
    return __builtin_bit_cast(float, (unsigned int)u << 16);
}

// ---------------- degree count (+rank) + x cast (fused) --------------------
// rank[i] = this edge's arrival index within its dst segment (free from the
// atomic we already pay), making the CSR fill atomic-free.
__global__ __launch_bounds__(256) void k_deg_cast(const int* __restrict__ dst,
                                                  int* __restrict__ deg,
                                                  int* __restrict__ rank, int e,
                                                  const float* __restrict__ x,
                                                  unsigned int* __restrict__ xb,
                                                  int total2) {
    int i = blockIdx.x * 256 + threadIdx.x;
    if (i < e) rank[i] = atomicAdd(&deg[dst[i]], 1);
    if (i < total2) {
        float2 v = ((const float2*)x)[i];
        xb[i] = (unsigned int)f2bf(v.x) | ((unsigned int)f2bf(v.y) << 16);
    }
}

// ---------------- hierarchical exclusive scan ----------------
__global__ __launch_bounds__(1024) void k_scan1(const int* __restrict__ deg,
                                                int* __restrict__ psum, int n) {
    __shared__ int red[1024];
    int tid = threadIdx.x;
    int i = blockIdx.x * 1024 + tid;
    red[tid] = (i < n) ? deg[i] : 0;
    __syncthreads();
#pragma unroll
    for (int off = 512; off > 0; off >>= 1) {
        if (tid < off) red[tid] += red[tid + off];
        __syncthreads();
    }
    if (tid == 0) psum[blockIdx.x] = red[0];
}

__global__ __launch_bounds__(128) void k_scan2(int* __restrict__ psum, int nb) {
    int tid = threadIdx.x;
    int d = (tid < nb) ? psum[tid] : 0;
    int v = d;
#pragma unroll
    for (int off = 1; off < 64; off <<= 1) {
        int u = __shfl_up(v, off, 64);
        if ((tid & 63) >= off) v += u;
    }
    __shared__ int ws[2];
    if ((tid & 63) == 63) ws[tid >> 6] = v;
    __syncthreads();
    int base = (tid >= 64) ? ws[0] : 0;
    if (tid < nb) psum[tid] = base + v - d;
}

__global__ __launch_bounds__(1024) void k_scan3(const int* __restrict__ deg,
                                                const int* __restrict__ psum,
                                                int* __restrict__ offs,
                                                float* __restrict__ dinv,
                                                int n, int e) {
    int tid = threadIdx.x;
    int i = blockIdx.x * 1024 + tid;
    int d = (i < n) ? deg[i] : 0;
    int v = d;
#pragma unroll
    for (int off = 1; off < 64; off <<= 1) {
        int u = __shfl_up(v, off, 64);
        if ((tid & 63) >= off) v += u;
    }
    __shared__ int wsum[16];
    int wid = tid >> 6;
    if ((tid & 63) == 63) wsum[wid] = v;
    __syncthreads();
    if (tid < 16) {
        int w = wsum[tid];
#pragma unroll
        for (int off = 1; off < 16; off <<= 1) {
            int u = __shfl_up(w, off, 64);
            if (tid >= off) w += u;
        }
        wsum[tid] = w;
    }
    __syncthreads();
    int base = psum[blockIdx.x] + (wid ? wsum[wid - 1] : 0);
    if (i < n) {
        offs[i] = base + v - d;
        dinv[i] = 1.0f / fmaxf((float)d, 1.0f);
    }
    if (i == 0) offs[n] = e;
}

// ---------------- CSR fill (atomic-free: pos = offs[dst] + rank) -----------
__global__ __launch_bounds__(256) void k_csr(const int* __restrict__ src,
                                             const int* __restrict__ dst,
                                             const int* __restrict__ rank,
                                             const int* __restrict__ offs,
                                             int* __restrict__ csr, int e) {
    int i = blockIdx.x * 256 + threadIdx.x;
    if (i < e) {
        csr[offs[dst[i]] + rank[i]] = src[i];
    }
}

// ---------------- weight pack into MFMA B-fragment order ----------------
static __device__ inline void pack_one(const float* __restrict__ W,
                                       unsigned short* __restrict__ out,
                                       int NTtot, int c_local, int nt,
                                       int chunkOff, int ncols, int lane) {
    int k = c_local * 32 + (lane >> 4) * 8;
    int n = nt * 16 + (lane & 15);
    unsigned short t[8];
#pragma unroll
    for (int j = 0; j < 8; j++) t[j] = f2bf(W[(size_t)(k + j) * ncols + n]);
    uint4 u;
    u.x = t[0] | ((unsigned)t[1] << 16);
    u.y = t[2] | ((unsigned)t[3] << 16);
    u.z = t[4] | ((unsigned)t[5] << 16);
    u.w = t[6] | ((unsigned)t[7] << 16);
    *(uint4*)&out[((size_t)((c_local + chunkOff) * NTtot + nt) * 64 + lane) * 8] = u;
}

__global__ __launch_bounds__(64) void k_packAll(const float* W1l, const float* W1r,
                                                const float* W2l, const float* W2r,
                                                const float* Wlin,
                                                unsigned short* p1, unsigned short* p2,
                                                unsigned short* ph) {
    int b = blockIdx.x, lane = threadIdx.x;
    if (b < 32)       pack_one(W1l, p1, 8, b >> 3, b & 7, 0, 128, lane);
    else if (b < 64)  { b -= 32; pack_one(W1r, p1, 8, b >> 3, b & 7, 4, 128, lane); }
    else if (b < 96)  { b -= 64; pack_one(W2l, p2, 8, b >> 3, b & 7, 0, 128, lane); }
    else if (b < 128) { b -= 96; pack_one(W2r, p2, 8, b >> 3, b & 7, 4, 128, lane); }
    else              { b -= 128; pack_one(Wlin, ph, 4, b >> 2, b & 3, 0, 64, lane); }
}

// ---------------- mean-aggregate (bf16): wave per node, 4 edges/issue -------
__global__ __launch_bounds__(256) void k_aggb(const uint4* __restrict__ feat4,
                                              const int* __restrict__ offs,
                                              const int* __restrict__ csr,
                                              const float* __restrict__ dinv,
                                              uint4* __restrict__ out4, int n) {
    int node = blockIdx.x * 4 + (threadIdx.x >> 6);
    if (node >= n) return;
    int lane = threadIdx.x & 63;
    int grp = lane >> 4;
    int ch = lane & 15;
    int beg = offs[node], end = offs[node + 1];

    float acc[8];
#pragma unroll
    for (int j = 0; j < 8; j++) acc[j] = 0.f;

    for (int i = beg; i < end; i += 8) {
        int e0 = i + grp;
        int e1 = i + 4 + grp;
        bool p0 = e0 < end, p1 = e1 < end;
        int s0 = p0 ? csr[e0] : 0;
        int s1 = p1 ? csr[e1] : 0;
        uint4 v0 = feat4[(size_t)s0 * 16 + ch];
        uint4 v1 = feat4[(size_t)s1 * 16 + ch];
        if (p0) {
            acc[0] += bflo(v0.x); acc[1] += bfhi(v0.x);
            acc[2] += bflo(v0.y); acc[3] += bfhi(v0.y);
            acc[4] += bflo(v0.z); acc[5] += bfhi(v0.z);
            acc[6] += bflo(v0.w); acc[7] += bfhi(v0.w);
        }
        if (p1) {
            acc[0] += bflo(v1.x); acc[1] += bfhi(v1.x);
            acc[2] += bflo(v1.y); acc[3] += bfhi(v1.y);
            acc[4] += bflo(v1.z); acc[5] += bfhi(v1.z);
            acc[6] += bflo(v1.w); acc[7] += bfhi(v1.w);
        }
    }
#pragma unroll
    for (int j = 0; j < 8; j++) {
        acc[j] += __shfl_xor(acc[j], 16);
        acc[j] += __shfl_xor(acc[j], 32);
    }
    if (grp == 0) {
        float di = dinv[node];
        uint4 o;
        o.x = (unsigned)f2bf(acc[0] * di) | ((unsigned)f2bf(acc[1] * di) << 16);
        o.y = (unsigned)f2bf(acc[2] * di) | ((unsigned)f2bf(acc[3] * di) << 16);
        o.z = (unsigned)f2bf(acc[4] * di) | ((unsigned)f2bf(acc[5] * di) << 16);
        o.w = (unsigned)f2bf(acc[6] * di) | ((unsigned)f2bf(acc[7] * di) << 16);
        out4[(size_t)node * 16 + ch] = o;
    }
}

// ---------------- MFMA GEMM ----------------
template <int NT, int KCH, bool TWO, bool RELU, bool RESID, bool OUTBF>
__global__ __launch_bounds__(256) void k_mfma(const unsigned short* __restrict__ P,
                                              const unsigned short* __restrict__ Q,
                                              const unsigned short* __restrict__ Wp,
                                              const float* __restrict__ bias,
                                              const unsigned short* __restrict__ resid,
                                              void* __restrict__ outv, int n) {
    const int lane = threadIdx.x & 63;
    const int wave = threadIdx.x >> 6;
    const int quad = lane >> 4;
    const int row0 = blockIdx.x * 64 + wave * 16;
    int rowA = row0 + (lane & 15);
    if (rowA >= n) rowA = n - 1;

    f32x4 acc[NT];
#pragma unroll
    for (int t = 0; t < NT; t++) acc[t] = (f32x4){0.f, 0.f, 0.f, 0.f};

#pragma unroll
    for (int c = 0; c < KCH; c++) {
        const unsigned short* Abase = (TWO && c >= KCH / 2) ? Q : P;
        const int kk = (TWO ? (c & (KCH / 2 - 1)) : c) * 32 + quad * 8;
        bf16x8 a = *(const bf16x8*)&Abase[(size_t)rowA * 128 + kk];
#pragma unroll
        for (int t = 0; t < NT; t++) {
            bf16x8 b = *(const bf16x8*)&Wp[(size_t)((c * NT + t) * 64 + lane) * 8];
            acc[t] = __builtin_amdgcn_mfma_f32_16x16x32_bf16(a, b, acc[t], 0, 0, 0);
        }
    }

    const int col = lane & 15;
#pragma unroll
    for (int t = 0; t < NT; t++) {
        float bv = bias[t * 16 + col];
#pragma unroll
        for (int r = 0; r < 4; r++) {
            int row = row0 + quad * 4 + r;
            if (row < n) {
                float v = acc[t][r] + bv;
                if (RESID) v += bf1(resid[(size_t)row * 128 + t * 16 + col]);
                if (RELU) v = fmaxf(v, 0.f);
                if (OUTBF)
                    ((unsigned short*)outv)[(size_t)row * (NT * 16) + t * 16 + col] = f2bf(v);
                else
                    ((float*)outv)[(size_t)row * (NT * 16) + t * 16 + col] = v;
            }
        }
    }
}

extern "C" void kernel_launch(void* const* d_in, const int* in_sizes, int n_in,
                              void* d_out, int out_size, void* d_ws, size_t ws_size,
                              hipStream_t stream) {
    const float* x    = (const float*)d_in[0];
    const int*   ei   = (const int*)d_in[1];
    const float* W1l  = (const float*)d_in[2];
    const float* b1   = (const float*)d_in[3];
    const float* W1r  = (const float*)d_in[4];
    const float* W2l  = (const float*)d_in[5];
    const float* b2   = (const float*)d_in[6];
    const float* W2r  = (const float*)d_in[7];
    const float* Wlin = (const float*)d_in[8];
    const float* blin = (const float*)d_in[9];
    float* out = (float*)d_out;

    const int N = NND, E = NED;
    const int* src = ei;
    const int* dst = ei + E;
    const int NB = (N + 1023) / 1024;

    char* w = (char*)d_ws;
    int*   deg    = (int*)w;               w += (size_t)N * 4;
    int*   offs   = (int*)w;               w += (size_t)(N + 4) * 4;
    float* dinv   = (float*)w;             w += (size_t)N * 4;
    int*   psum   = (int*)w;               w += (size_t)((NB + 3) & ~3) * 4;
    int*   rank   = (int*)w;               w += (size_t)E * 4;
    int*   csr    = (int*)w;               w += (size_t)E * 4;
    unsigned short* p1  = (unsigned short*)w;  w += 256 * 128 * 2;
    unsigned short* p2  = (unsigned short*)w;  w += 256 * 128 * 2;
    unsigned short* ph  = (unsigned short*)w;  w += 128 * 64 * 2;
    unsigned short* xb  = (unsigned short*)w;  w += (size_t)N * 128 * 2;
    unsigned short* agg = (unsigned short*)w;  w += (size_t)N * 128 * 2;
    unsigned short* h1  = (unsigned short*)w;  w += (size_t)N * 128 * 2;
    unsigned short* h2  = (unsigned short*)w;  w += (size_t)N * 128 * 2;

    hipMemsetAsync(deg, 0, (size_t)N * 4, stream);

    k_deg_cast<<<(N * 64 + 255) / 256, 256, 0, stream>>>(dst, deg, rank, E, x,
                                                         (unsigned int*)xb, N * 64);
    k_scan1<<<NB, 1024, 0, stream>>>(deg, psum, N);
    k_scan2<<<1, 128, 0, stream>>>(psum, NB);
    k_scan3<<<NB, 1024, 0, stream>>>(deg, psum, offs, dinv, N, E);
    k_csr<<<E / 256, 256, 0, stream>>>(src, dst, rank, offs, csr, E);
    k_packAll<<<144, 64, 0, stream>>>(W1l, W1r, W2l, W2r, Wlin, p1, p2, ph);

    // layer 1
    k_aggb<<<(N + 3) / 4, 256, 0, stream>>>((const uint4*)xb, offs, csr, dinv,
                                            (uint4*)agg, N);
    k_mfma<8, 8, true, true, false, true><<<(N + 63) / 64, 256, 0, stream>>>(
        agg, xb, p1, b1, nullptr, h1, N);

    // layer 2
    k_aggb<<<(N + 3) / 4, 256, 0, stream>>>((const uint4*)h1, offs, csr, dinv,
                                            (uint4*)agg, N);
    k_mfma<8, 8, true, true, true, true><<<(N + 63) / 64, 256, 0, stream>>>(
        agg, h1, p2, b2, h1, h2, N);

    // head
    k_mfma<4, 4, false, false, false, false><<<(N + 63) / 64, 256, 0, stream>>>(
        h2, nullptr, ph, blin, nullptr, out, N);
}

// Round 6
// 443.756 us; speedup vs baseline: 2.2085x; 1.0607x over previous
//
#include <hip/hip_runtime.h>
#include <hip/hip_bf16.h>
#include <cstdint>

#define NND 100000
#define NED 1600000
#define FIN 128
#define FOUT 64

typedef __bf16 bf16x8 __attribute__((ext_vector_type(8)));
typedef float f32x4 __attribute__((ext_vector_type(4)));

static __device__ inline unsigned short f2bf(float f) {
    unsigned int u = __builtin_bit_cast(unsigned int, f);
    unsigned int r = (u + 0x7fffu + ((u >> 16) & 1u)) >> 16;  // RNE
    return (unsigned short)r;
}
static __device__ inline float bflo(unsigned int v) {
    return __builtin_bit_cast(float, v << 16);
}
static __device__ inline float bfhi(unsigned int v) {
    return __builtin_bit_cast(float, v & 0xffff0000u);
}
static __device__ inline float bf1(unsigned short u) {
    return __builtin_bit_cast(float, (unsigned int)u << 16);
}

// ---------------- degree count (+rank) + x cast (fused) --------------------
__global__ __launch_bounds__(256) void k_deg_cast(const int* __restrict__ dst,
                                                  int* __restrict__ deg,
                                                  int* __restrict__ rank, int e,
                                                  const float* __restrict__ x,
                                                  unsigned int* __restrict__ xb,
                                                  int total2) {
    int i = blockIdx.x * 256 + threadIdx.x;
    if (i < e) rank[i] = atomicAdd(&deg[dst[i]], 1);
    if (i < total2) {
        float2 v = ((const float2*)x)[i];
        xb[i] = (unsigned int)f2bf(v.x) | ((unsigned int)f2bf(v.y) << 16);
    }
}

// ---------------- hierarchical exclusive scan ----------------
__global__ __launch_bounds__(1024) void k_scan1(const int* __restrict__ deg,
                                                int* __restrict__ psum, int n) {
    __shared__ int red[1024];
    int tid = threadIdx.x;
    int i = blockIdx.x * 1024 + tid;
    red[tid] = (i < n) ? deg[i] : 0;
    __syncthreads();
#pragma unroll
    for (int off = 512; off > 0; off >>= 1) {
        if (tid < off) red[tid] += red[tid + off];
        __syncthreads();
    }
    if (tid == 0) psum[blockIdx.x] = red[0];
}

__global__ __launch_bounds__(128) void k_scan2(int* __restrict__ psum, int nb) {
    int tid = threadIdx.x;
    int d = (tid < nb) ? psum[tid] : 0;
    int v = d;
#pragma unroll
    for (int off = 1; off < 64; off <<= 1) {
        int u = __shfl_up(v, off, 64);
        if ((tid & 63) >= off) v += u;
    }
    __shared__ int ws[2];
    if ((tid & 63) == 63) ws[tid >> 6] = v;
    __syncthreads();
    int base = (tid >= 64) ? ws[0] : 0;
    if (tid < nb) psum[tid] = base + v - d;
}

__global__ __launch_bounds__(1024) void k_scan3(const int* __restrict__ deg,
                                                const int* __restrict__ psum,
                                                int* __restrict__ offs,
                                                float* __restrict__ dinv,
                                                int n, int e) {
    int tid = threadIdx.x;
    int i = blockIdx.x * 1024 + tid;
    int d = (i < n) ? deg[i] : 0;
    int v = d;
#pragma unroll
    for (int off = 1; off < 64; off <<= 1) {
        int u = __shfl_up(v, off, 64);
        if ((tid & 63) >= off) v += u;
    }
    __shared__ int wsum[16];
    int wid = tid >> 6;
    if ((tid & 63) == 63) wsum[wid] = v;
    __syncthreads();
    if (tid < 16) {
        int w = wsum[tid];
#pragma unroll
        for (int off = 1; off < 16; off <<= 1) {
            int u = __shfl_up(w, off, 64);
            if (tid >= off) w += u;
        }
        wsum[tid] = w;
    }
    __syncthreads();
    int base = psum[blockIdx.x] + (wid ? wsum[wid - 1] : 0);
    if (i < n) {
        offs[i] = base + v - d;
        dinv[i] = 1.0f / fmaxf((float)d, 1.0f);
    }
    if (i == 0) offs[n] = e;
}

// ---------------- CSR fill (atomic-free) ----------------
__global__ __launch_bounds__(256) void k_csr(const int* __restrict__ src,
                                             const int* __restrict__ dst,
                                             const int* __restrict__ rank,
                                             const int* __restrict__ offs,
                                             int* __restrict__ csr, int e) {
    int i = blockIdx.x * 256 + threadIdx.x;
    if (i < e) {
        csr[offs[dst[i]] + rank[i]] = src[i];
    }
}

// ---------------- weight pack into MFMA B-fragment order ----------------
static __device__ inline void pack_one(const float* __restrict__ W,
                                       unsigned short* __restrict__ out,
                                       int NTtot, int c_local, int nt,
                                       int chunkOff, int ncols, int lane) {
    int k = c_local * 32 + (lane >> 4) * 8;
    int n = nt * 16 + (lane & 15);
    unsigned short t[8];
#pragma unroll
    for (int j = 0; j < 8; j++) t[j] = f2bf(W[(size_t)(k + j) * ncols + n]);
    uint4 u;
    u.x = t[0] | ((unsigned)t[1] << 16);
    u.y = t[2] | ((unsigned)t[3] << 16);
    u.z = t[4] | ((unsigned)t[5] << 16);
    u.w = t[6] | ((unsigned)t[7] << 16);
    *(uint4*)&out[((size_t)((c_local + chunkOff) * NTtot + nt) * 64 + lane) * 8] = u;
}

__global__ __launch_bounds__(64) void k_packAll(const float* W1l, const float* W1r,
                                                const float* W2l, const float* W2r,
                                                const float* Wlin,
                                                unsigned short* p1, unsigned short* p2,
                                                unsigned short* ph) {
    int b = blockIdx.x, lane = threadIdx.x;
    if (b < 32)       pack_one(W1l, p1, 8, b >> 3, b & 7, 0, 128, lane);
    else if (b < 64)  { b -= 32; pack_one(W1r, p1, 8, b >> 3, b & 7, 4, 128, lane); }
    else if (b < 96)  { b -= 64; pack_one(W2l, p2, 8, b >> 3, b & 7, 0, 128, lane); }
    else if (b < 128) { b -= 96; pack_one(W2r, p2, 8, b >> 3, b & 7, 4, 128, lane); }
    else              { b -= 128; pack_one(Wlin, ph, 4, b >> 2, b & 3, 0, 64, lane); }
}

// ---------------- mean-aggregate: wave/node, 16 edges in flight ------------
#define ACC8(v) do { \
    acc[0].x += bflo((v).x); acc[0].y += bfhi((v).x); \
    acc[1].x += bflo((v).y); acc[1].y += bfhi((v).y); \
    acc[2].x += bflo((v).z); acc[2].y += bfhi((v).z); \
    acc[3].x += bflo((v).w); acc[3].y += bfhi((v).w); } while (0)

__global__ __launch_bounds__(256) void k_aggb(const uint4* __restrict__ feat4,
                                              const int* __restrict__ offs,
                                              const int* __restrict__ csr,
                                              const float* __restrict__ dinv,
                                              uint4* __restrict__ out4, int n) {
    int node = blockIdx.x * 4 + (threadIdx.x >> 6);
    if (node >= n) return;
    int lane = threadIdx.x & 63;
    int grp = lane >> 4;
    int ch = lane & 15;
    int beg = offs[node], end = offs[node + 1];
    int deg = end - beg;

    float2 acc[4];
#pragma unroll
    for (int j = 0; j < 4; j++) acc[j] = make_float2(0.f, 0.f);

    int i = beg;
    int fullEnd = beg + (deg & ~15);
    for (; i < fullEnd; i += 16) {  // 16 edges, 4 gathers in flight, no masks
        int s0 = csr[i + grp];
        int s1 = csr[i + 4 + grp];
        int s2 = csr[i + 8 + grp];
        int s3 = csr[i + 12 + grp];
        uint4 v0 = feat4[(size_t)s0 * 16 + ch];
        uint4 v1 = feat4[(size_t)s1 * 16 + ch];
        uint4 v2 = feat4[(size_t)s2 * 16 + ch];
        uint4 v3 = feat4[(size_t)s3 * 16 + ch];
        ACC8(v0); ACC8(v1); ACC8(v2); ACC8(v3);
    }
    if (i < end) {  // tail <= 15 edges, predicated
#pragma unroll
        for (int g = 0; g < 4; g++) {
            int e = i + g * 4 + grp;
            bool p = e < end;
            int s = csr[p ? e : beg];
            uint4 v = feat4[(size_t)s * 16 + ch];
            if (p) { ACC8(v); }
        }
    }
#pragma unroll
    for (int j = 0; j < 4; j++) {
        acc[j].x += __shfl_xor(acc[j].x, 16);
        acc[j].y += __shfl_xor(acc[j].y, 16);
        acc[j].x += __shfl_xor(acc[j].x, 32);
        acc[j].y += __shfl_xor(acc[j].y, 32);
    }
    if (grp == 0) {
        float di = dinv[node];
        uint4 o;
        o.x = (unsigned)f2bf(acc[0].x * di) | ((unsigned)f2bf(acc[0].y * di) << 16);
        o.y = (unsigned)f2bf(acc[1].x * di) | ((unsigned)f2bf(acc[1].y * di) << 16);
        o.z = (unsigned)f2bf(acc[2].x * di) | ((unsigned)f2bf(acc[2].y * di) << 16);
        o.w = (unsigned)f2bf(acc[3].x * di) | ((unsigned)f2bf(acc[3].y * di) << 16);
        out4[(size_t)node * 16 + ch] = o;
    }
}

// ---------------- MFMA GEMM (+optional fused head) ----------------
// HEAD: instead of storing the layer output, transpose it through per-wave
// LDS into A-fragments and run a second GEMM (K=128 -> 64 cols, fp32 out).
template <int NT, int KCH, bool TWO, bool RELU, bool RESID, bool HEAD, bool OUTBF>
__global__ __launch_bounds__(256) void k_mfma(const unsigned short* __restrict__ P,
                                              const unsigned short* __restrict__ Q,
                                              const unsigned short* __restrict__ Wp,
                                              const float* __restrict__ bias,
                                              const unsigned short* __restrict__ resid,
                                              const unsigned short* __restrict__ Wp2,
                                              const float* __restrict__ bias2,
                                              void* __restrict__ outv, int n) {
    const int lane = threadIdx.x & 63;
    const int wave = threadIdx.x >> 6;
    const int quad = lane >> 4;
    const int row0 = blockIdx.x * 64 + wave * 16;
    int rowA = row0 + (lane & 15);
    if (rowA >= n) rowA = n - 1;

    f32x4 acc[NT];
#pragma unroll
    for (int t = 0; t < NT; t++) acc[t] = (f32x4){0.f, 0.f, 0.f, 0.f};

#pragma unroll
    for (int c = 0; c < KCH; c++) {
        const unsigned short* Abase = (TWO && c >= KCH / 2) ? Q : P;
        const int kk = (TWO ? (c & (KCH / 2 - 1)) : c) * 32 + quad * 8;
        bf16x8 a = *(const bf16x8*)&Abase[(size_t)rowA * 128 + kk];
#pragma unroll
        for (int t = 0; t < NT; t++) {
            bf16x8 b = *(const bf16x8*)&Wp[(size_t)((c * NT + t) * 64 + lane) * 8];
            acc[t] = __builtin_amdgcn_mfma_f32_16x16x32_bf16(a, b, acc[t], 0, 0, 0);
        }
    }

    const int col = lane & 15;
    if (!HEAD) {
#pragma unroll
        for (int t = 0; t < NT; t++) {
            float bv = bias[t * 16 + col];
#pragma unroll
            for (int r = 0; r < 4; r++) {
                int row = row0 + quad * 4 + r;
                if (row < n) {
                    float v = acc[t][r] + bv;
                    if (RESID) v += bf1(resid[(size_t)row * 128 + t * 16 + col]);
                    if (RELU) v = fmaxf(v, 0.f);
                    if (OUTBF)
                        ((unsigned short*)outv)[(size_t)row * (NT * 16) + t * 16 + col] = f2bf(v);
                    else
                        ((float*)outv)[(size_t)row * (NT * 16) + t * 16 + col] = v;
                }
            }
        }
    } else {
        // epilogue -> per-wave LDS transpose (row-major, stride 136 to break
        // bank alignment), wave-private region: no __syncthreads needed.
        __shared__ __align__(16) unsigned short sT[4][16 * 136];
#pragma unroll
        for (int t = 0; t < NT; t++) {
            float bv = bias[t * 16 + col];
#pragma unroll
            for (int r = 0; r < 4; r++) {
                int row = row0 + quad * 4 + r;
                int rr = row < n ? row : n - 1;  // clamp resid read; junk masked later
                float v = acc[t][r] + bv;
                if (RESID) v += bf1(resid[(size_t)rr * 128 + t * 16 + col]);
                if (RELU) v = fmaxf(v, 0.f);
                sT[wave][(quad * 4 + r) * 136 + t * 16 + col] = f2bf(v);
            }
        }
        // head GEMM: A from LDS (m=lane&15, k=c*32+quad*8..), B=Wp2, 64 cols
        f32x4 hacc[4];
#pragma unroll
        for (int t = 0; t < 4; t++) hacc[t] = (f32x4){0.f, 0.f, 0.f, 0.f};
#pragma unroll
        for (int c = 0; c < 4; c++) {
            bf16x8 a = *(const bf16x8*)&sT[wave][(lane & 15) * 136 + c * 32 + quad * 8];
#pragma unroll
            for (int t = 0; t < 4; t++) {
                bf16x8 b = *(const bf16x8*)&Wp2[(size_t)((c * 4 + t) * 64 + lane) * 8];
                hacc[t] = __builtin_amdgcn_mfma_f32_16x16x32_bf16(a, b, hacc[t], 0, 0, 0);
            }
        }
#pragma unroll
        for (int t = 0; t < 4; t++) {
            float bv = bias2[t * 16 + col];
#pragma unroll
            for (int r = 0; r < 4; r++) {
                int row = row0 + quad * 4 + r;
                if (row < n)
                    ((float*)outv)[(size_t)row * 64 + t * 16 + col] = hacc[t][r] + bv;
            }
        }
    }
}

extern "C" void kernel_launch(void* const* d_in, const int* in_sizes, int n_in,
                              void* d_out, int out_size, void* d_ws, size_t ws_size,
                              hipStream_t stream) {
    const float* x    = (const float*)d_in[0];
    const int*   ei   = (const int*)d_in[1];
    const float* W1l  = (const float*)d_in[2];
    const float* b1   = (const float*)d_in[3];
    const float* W1r  = (const float*)d_in[4];
    const float* W2l  = (const float*)d_in[5];
    const float* b2   = (const float*)d_in[6];
    const float* W2r  = (const float*)d_in[7];
    const float* Wlin = (const float*)d_in[8];
    const float* blin = (const float*)d_in[9];
    float* out = (float*)d_out;

    const int N = NND, E = NED;
    const int* src = ei;
    const int* dst = ei + E;
    const int NB = (N + 1023) / 1024;

    char* w = (char*)d_ws;
    int*   deg    = (int*)w;               w += (size_t)N * 4;
    int*   offs   = (int*)w;               w += (size_t)(N + 4) * 4;
    float* dinv   = (float*)w;             w += (size_t)N * 4;
    int*   psum   = (int*)w;               w += (size_t)((NB + 3) & ~3) * 4;
    int*   rank   = (int*)w;               w += (size_t)E * 4;
    int*   csr    = (int*)w;               w += (size_t)E * 4;
    unsigned short* p1  = (unsigned short*)w;  w += 256 * 128 * 2;
    unsigned short* p2  = (unsigned short*)w;  w += 256 * 128 * 2;
    unsigned short* ph  = (unsigned short*)w;  w += 128 * 64 * 2;
    unsigned short* xb  = (unsigned short*)w;  w += (size_t)N * 128 * 2;
    unsigned short* agg = (unsigned short*)w;  w += (size_t)N * 128 * 2;
    unsigned short* h1  = (unsigned short*)w;  w += (size_t)N * 128 * 2;

    hipMemsetAsync(deg, 0, (size_t)N * 4, stream);

    k_deg_cast<<<(N * 64 + 255) / 256, 256, 0, stream>>>(dst, deg, rank, E, x,
                                                         (unsigned int*)xb, N * 64);
    k_scan1<<<NB, 1024, 0, stream>>>(deg, psum, N);
    k_scan2<<<1, 128, 0, stream>>>(psum, NB);
    k_scan3<<<NB, 1024, 0, stream>>>(deg, psum, offs, dinv, N, E);
    k_csr<<<E / 256, 256, 0, stream>>>(src, dst, rank, offs, csr, E);
    k_packAll<<<144, 64, 0, stream>>>(W1l, W1r, W2l, W2r, Wlin, p1, p2, ph);

    // layer 1: h1 = relu([agg|xb] @ [W1l;W1r] + b1)
    k_aggb<<<(N + 3) / 4, 256, 0, stream>>>((const uint4*)xb, offs, csr, dinv,
                                            (uint4*)agg, N);
    k_mfma<8, 8, true, true, false, false, true><<<(N + 63) / 64, 256, 0, stream>>>(
        agg, xb, p1, b1, nullptr, nullptr, nullptr, h1, N);

    // layer 2 + head fused: out = (relu(h1 + [agg|h1]@[W2l;W2r] + b2)) @ Wlin + blin
    k_aggb<<<(N + 3) / 4, 256, 0, stream>>>((const uint4*)h1, offs, csr, dinv,
                                            (uint4*)agg, N);
    k_mfma<8, 8, true, true, true, true, false><<<(N + 63) / 64, 256, 0, stream>>>(
        agg, h1, p2, b2, h1, ph, blin, out, N);
}

// Round 7
// 442.638 us; speedup vs baseline: 2.2141x; 1.0025x over previous
//
#include <hip/hip_runtime.h>
#include <hip/hip_bf16.h>
#include <cstdint>

#define NND 100000
#define NED 1600000
#define FIN 128
#define FOUT 64
#define NREP 8   // counter replicas to break same-address atomic serialization

typedef __bf16 bf16x8 __attribute__((ext_vector_type(8)));
typedef float f32x4 __attribute__((ext_vector_type(4)));

static __device__ inline unsigned short f2bf(float f) {
    unsigned int u = __builtin_bit_cast(unsigned int, f);
    unsigned int r = (u + 0x7fffu + ((u >> 16) & 1u)) >> 16;  // RNE
    return (unsigned short)r;
}
static __device__ inline float bflo(unsigned int v) {
    return __builtin_bit_cast(float, v << 16);
}
static __device__ inline float bfhi(unsigned int v) {
    return __builtin_bit_cast(float, v & 0xffff0000u);
}
static __device__ inline float bf1(unsigned short u) {
    return __builtin_bit_cast(float, (unsigned int)u << 16);
}

// ---------------- degree count (+rank, 8-way replicated) + x cast ----------
__global__ __launch_bounds__(256) void k_deg_cast(const int* __restrict__ dst,
                                                  int* __restrict__ deg8,
                                                  int* __restrict__ rank, int e,
                                                  const float* __restrict__ x,
                                                  unsigned int* __restrict__ xb,
                                                  int total2) {
    int i = blockIdx.x * 256 + threadIdx.x;
    if (i < e) {
        int r = (i >> 8) & (NREP - 1);  // replica: uniform per block
        rank[i] = atomicAdd(&deg8[r * NND + dst[i]], 1);
    }
    if (i < total2) {
        float2 v = ((const float2*)x)[i];
        xb[i] = (unsigned int)f2bf(v.x) | ((unsigned int)f2bf(v.y) << 16);
    }
}

// ---------------- hierarchical exclusive scan ----------------
// phase 1: per-block sums of total degree (sum across replicas)
__global__ __launch_bounds__(1024) void k_scan1(const int* __restrict__ deg8,
                                                int* __restrict__ psum, int n) {
    __shared__ int red[1024];
    int tid = threadIdx.x;
    int i = blockIdx.x * 1024 + tid;
    int s = 0;
    if (i < n) {
#pragma unroll
        for (int r = 0; r < NREP; r++) s += deg8[r * NND + i];
    }
    red[tid] = s;
    __syncthreads();
#pragma unroll
    for (int off = 512; off > 0; off >>= 1) {
        if (tid < off) red[tid] += red[tid + off];
        __syncthreads();
    }
    if (tid == 0) psum[blockIdx.x] = red[0];
}

__global__ __launch_bounds__(128) void k_scan2(int* __restrict__ psum, int nb) {
    int tid = threadIdx.x;
    int d = (tid < nb) ? psum[tid] : 0;
    int v = d;
#pragma unroll
    for (int off = 1; off < 64; off <<= 1) {
        int u = __shfl_up(v, off, 64);
        if ((tid & 63) >= off) v += u;
    }
    __shared__ int ws[2];
    if ((tid & 63) == 63) ws[tid >> 6] = v;
    __syncthreads();
    int base = (tid >= 64) ? ws[0] : 0;
    if (tid < nb) psum[tid] = base + v - d;
}

// phase 3: node offsets + per-replica bases + dinv
__global__ __launch_bounds__(1024) void k_scan3(const int* __restrict__ deg8,
                                                const int* __restrict__ psum,
                                                int* __restrict__ offs,
                                                int* __restrict__ repb,
                                                float* __restrict__ dinv,
                                                int n, int e) {
    int tid = threadIdx.x;
    int i = blockIdx.x * 1024 + tid;
    int dr[NREP];
    int d = 0;
    if (i < n) {
#pragma unroll
        for (int r = 0; r < NREP; r++) { dr[r] = deg8[r * NND + i]; d += dr[r]; }
    }
    int v = d;
#pragma unroll
    for (int off = 1; off < 64; off <<= 1) {
        int u = __shfl_up(v, off, 64);
        if ((tid & 63) >= off) v += u;
    }
    __shared__ int wsum[16];
    int wid = tid >> 6;
    if ((tid & 63) == 63) wsum[wid] = v;
    __syncthreads();
    if (tid < 16) {
        int w = wsum[tid];
#pragma unroll
        for (int off = 1; off < 16; off <<= 1) {
            int u = __shfl_up(w, off, 64);
            if (tid >= off) w += u;
        }
        wsum[tid] = w;
    }
    __syncthreads();
    int base = psum[blockIdx.x] + (wid ? wsum[wid - 1] : 0);
    if (i < n) {
        int o = base + v - d;  // exclusive node offset
        offs[i] = o;
        dinv[i] = 1.0f / fmaxf((float)d, 1.0f);
        int run = o;
#pragma unroll
        for (int r = 0; r < NREP; r++) { repb[r * NND + i] = run; run += dr[r]; }
    }
    if (i == 0) offs[n] = e;
}

// ---------------- CSR fill (atomic-free: pos = repb[r][dst] + rank) --------
__global__ __launch_bounds__(256) void k_csr(const int* __restrict__ src,
                                             const int* __restrict__ dst,
                                             const int* __restrict__ rank,
                                             const int* __restrict__ repb,
                                             int* __restrict__ csr, int e) {
    int i = blockIdx.x * 256 + threadIdx.x;
    if (i < e) {
        int r = (i >> 8) & (NREP - 1);
        csr[repb[r * NND + dst[i]] + rank[i]] = src[i];
    }
}

// ---------------- weight pack into MFMA B-fragment order ----------------
static __device__ inline void pack_one(const float* __restrict__ W,
                                       unsigned short* __restrict__ out,
                                       int NTtot, int c_local, int nt,
                                       int chunkOff, int ncols, int lane) {
    int k = c_local * 32 + (lane >> 4) * 8;
    int n = nt * 16 + (lane & 15);
    unsigned short t[8];
#pragma unroll
    for (int j = 0; j < 8; j++) t[j] = f2bf(W[(size_t)(k + j) * ncols + n]);
    uint4 u;
    u.x = t[0] | ((unsigned)t[1] << 16);
    u.y = t[2] | ((unsigned)t[3] << 16);
    u.z = t[4] | ((unsigned)t[5] << 16);
    u.w = t[6] | ((unsigned)t[7] << 16);
    *(uint4*)&out[((size_t)((c_local + chunkOff) * NTtot + nt) * 64 + lane) * 8] = u;
}

__global__ __launch_bounds__(64) void k_packAll(const float* W1l, const float* W1r,
                                                const float* W2l, const float* W2r,
                                                const float* Wlin,
                                                unsigned short* p1, unsigned short* p2,
                                                unsigned short* ph) {
    int b = blockIdx.x, lane = threadIdx.x;
    if (b < 32)       pack_one(W1l, p1, 8, b >> 3, b & 7, 0, 128, lane);
    else if (b < 64)  { b -= 32; pack_one(W1r, p1, 8, b >> 3, b & 7, 4, 128, lane); }
    else if (b < 96)  { b -= 64; pack_one(W2l, p2, 8, b >> 3, b & 7, 0, 128, lane); }
    else if (b < 128) { b -= 96; pack_one(W2r, p2, 8, b >> 3, b & 7, 4, 128, lane); }
    else              { b -= 128; pack_one(Wlin, ph, 4, b >> 2, b & 3, 0, 64, lane); }
}

// ---------------- mean-aggregate: wave/node, 16 edges in flight ------------
#define ACC8(v) do { \
    acc[0].x += bflo((v).x); acc[0].y += bfhi((v).x); \
    acc[1].x += bflo((v).y); acc[1].y += bfhi((v).y); \
    acc[2].x += bflo((v).z); acc[2].y += bfhi((v).z); \
    acc[3].x += bflo((v).w); acc[3].y += bfhi((v).w); } while (0)

__global__ __launch_bounds__(256) void k_aggb(const uint4* __restrict__ feat4,
                                              const int* __restrict__ offs,
                                              const int* __restrict__ csr,
                                              const float* __restrict__ dinv,
                                              uint4* __restrict__ out4, int n) {
    int node = blockIdx.x * 4 + (threadIdx.x >> 6);
    if (node >= n) return;
    int lane = threadIdx.x & 63;
    int grp = lane >> 4;
    int ch = lane & 15;
    int beg = offs[node], end = offs[node + 1];
    int deg = end - beg;

    float2 acc[4];
#pragma unroll
    for (int j = 0; j < 4; j++) acc[j] = make_float2(0.f, 0.f);

    int i = beg;
    int fullEnd = beg + (deg & ~15);
    for (; i < fullEnd; i += 16) {
        int s0 = csr[i + grp];
        int s1 = csr[i + 4 + grp];
        int s2 = csr[i + 8 + grp];
        int s3 = csr[i + 12 + grp];
        uint4 v0 = feat4[(size_t)s0 * 16 + ch];
        uint4 v1 = feat4[(size_t)s1 * 16 + ch];
        uint4 v2 = feat4[(size_t)s2 * 16 + ch];
        uint4 v3 = feat4[(size_t)s3 * 16 + ch];
        ACC8(v0); ACC8(v1); ACC8(v2); ACC8(v3);
    }
    if (i < end) {
#pragma unroll
        for (int g = 0; g < 4; g++) {
            int e = i + g * 4 + grp;
            bool p = e < end;
            int s = csr[p ? e : beg];
            uint4 v = feat4[(size_t)s * 16 + ch];
            if (p) { ACC8(v); }
        }
    }
#pragma unroll
    for (int j = 0; j < 4; j++) {
        acc[j].x += __shfl_xor(acc[j].x, 16);
        acc[j].y += __shfl_xor(acc[j].y, 16);
        acc[j].x += __shfl_xor(acc[j].x, 32);
        acc[j].y += __shfl_xor(acc[j].y, 32);
    }
    if (grp == 0) {
        float di = dinv[node];
        uint4 o;
        o.x = (unsigned)f2bf(acc[0].x * di) | ((unsigned)f2bf(acc[0].y * di) << 16);
        o.y = (unsigned)f2bf(acc[1].x * di) | ((unsigned)f2bf(acc[1].y * di) << 16);
        o.z = (unsigned)f2bf(acc[2].x * di) | ((unsigned)f2bf(acc[2].y * di) << 16);
        o.w = (unsigned)f2bf(acc[3].x * di) | ((unsigned)f2bf(acc[3].y * di) << 16);
        out4[(size_t)node * 16 + ch] = o;
    }
}

// ---------------- MFMA GEMM (+optional fused head) ----------------
template <int NT, int KCH, bool TWO, bool RELU, bool RESID, bool HEAD, bool OUTBF>
__global__ __launch_bounds__(256) void k_mfma(const unsigned short* __restrict__ P,
                                              const unsigned short* __restrict__ Q,
                                              const unsigned short* __restrict__ Wp,
                                              const float* __restrict__ bias,
                                              const unsigned short* __restrict__ resid,
                                              const unsigned short* __restrict__ Wp2,
                                              const float* __restrict__ bias2,
                                              void* __restrict__ outv, int n) {
    const int lane = threadIdx.x & 63;
    const int wave = threadIdx.x >> 6;
    const int quad = lane >> 4;
    const int row0 = blockIdx.x * 64 + wave * 16;
    int rowA = row0 + (lane & 15);
    if (rowA >= n) rowA = n - 1;

    f32x4 acc[NT];
#pragma unroll
    for (int t = 0; t < NT; t++) acc[t] = (f32x4){0.f, 0.f, 0.f, 0.f};

#pragma unroll
    for (int c = 0; c < KCH; c++) {
        const unsigned short* Abase = (TWO && c >= KCH / 2) ? Q : P;
        const int kk = (TWO ? (c & (KCH / 2 - 1)) : c) * 32 + quad * 8;
        bf16x8 a = *(const bf16x8*)&Abase[(size_t)rowA * 128 + kk];
#pragma unroll
        for (int t = 0; t < NT; t++) {
            bf16x8 b = *(const bf16x8*)&Wp[(size_t)((c * NT + t) * 64 + lane) * 8];
            acc[t] = __builtin_amdgcn_mfma_f32_16x16x32_bf16(a, b, acc[t], 0, 0, 0);
        }
    }

    const int col = lane & 15;
    if (!HEAD) {
#pragma unroll
        for (int t = 0; t < NT; t++) {
            float bv = bias[t * 16 + col];
#pragma unroll
            for (int r = 0; r < 4; r++) {
                int row = row0 + quad * 4 + r;
                if (row < n) {
                    float v = acc[t][r] + bv;
                    if (RESID) v += bf1(resid[(size_t)row * 128 + t * 16 + col]);
                    if (RELU) v = fmaxf(v, 0.f);
                    if (OUTBF)
                        ((unsigned short*)outv)[(size_t)row * (NT * 16) + t * 16 + col] = f2bf(v);
                    else
                        ((float*)outv)[(size_t)row * (NT * 16) + t * 16 + col] = v;
                }
            }
        }
    } else {
        __shared__ __align__(16) unsigned short sT[4][16 * 136];
#pragma unroll
        for (int t = 0; t < NT; t++) {
            float bv = bias[t * 16 + col];
#pragma unroll
            for (int r = 0; r < 4; r++) {
                int row = row0 + quad * 4 + r;
                int rr = row < n ? row : n - 1;
                float v = acc[t][r] + bv;
                if (RESID) v += bf1(resid[(size_t)rr * 128 + t * 16 + col]);
                if (RELU) v = fmaxf(v, 0.f);
                sT[wave][(quad * 4 + r) * 136 + t * 16 + col] = f2bf(v);
            }
        }
        f32x4 hacc[4];
#pragma unroll
        for (int t = 0; t < 4; t++) hacc[t] = (f32x4){0.f, 0.f, 0.f, 0.f};
#pragma unroll
        for (int c = 0; c < 4; c++) {
            bf16x8 a = *(const bf16x8*)&sT[wave][(lane & 15) * 136 + c * 32 + quad * 8];
#pragma unroll
            for (int t = 0; t < 4; t++) {
                bf16x8 b = *(const bf16x8*)&Wp2[(size_t)((c * 4 + t) * 64 + lane) * 8];
                hacc[t] = __builtin_amdgcn_mfma_f32_16x16x32_bf16(a, b, hacc[t], 0, 0, 0);
            }
        }
#pragma unroll
        for (int t = 0; t < 4; t++) {
            float bv = bias2[t * 16 + col];
#pragma unroll
            for (int r = 0; r < 4; r++) {
                int row = row0 + quad * 4 + r;
                if (row < n)
                    ((float*)outv)[(size_t)row * 64 + t * 16 + col] = hacc[t][r] + bv;
            }
        }
    }
}

extern "C" void kernel_launch(void* const* d_in, const int* in_sizes, int n_in,
                              void* d_out, int out_size, void* d_ws, size_t ws_size,
                              hipStream_t stream) {
    const float* x    = (const float*)d_in[0];
    const int*   ei   = (const int*)d_in[1];
    const float* W1l  = (const float*)d_in[2];
    const float* b1   = (const float*)d_in[3];
    const float* W1r  = (const float*)d_in[4];
    const float* W2l  = (const float*)d_in[5];
    const float* b2   = (const float*)d_in[6];
    const float* W2r  = (const float*)d_in[7];
    const float* Wlin = (const float*)d_in[8];
    const float* blin = (const float*)d_in[9];
    float* out = (float*)d_out;

    const int N = NND, E = NED;
    const int* src = ei;
    const int* dst = ei + E;
    const int NB = (N + 1023) / 1024;

    char* w = (char*)d_ws;
    int*   deg8   = (int*)w;               w += (size_t)NREP * N * 4;  // zeroed
    int*   offs   = (int*)w;               w += (size_t)(N + 4) * 4;
    int*   repb   = (int*)w;               w += (size_t)NREP * N * 4;
    float* dinv   = (float*)w;             w += (size_t)N * 4;
    int*   psum   = (int*)w;               w += (size_t)((NB + 3) & ~3) * 4;
    int*   rank   = (int*)w;               w += (size_t)E * 4;
    int*   csr    = (int*)w;               w += (size_t)E * 4;
    unsigned short* p1  = (unsigned short*)w;  w += 256 * 128 * 2;
    unsigned short* p2  = (unsigned short*)w;  w += 256 * 128 * 2;
    unsigned short* ph  = (unsigned short*)w;  w += 128 * 64 * 2;
    unsigned short* xb  = (unsigned short*)w;  w += (size_t)N * 128 * 2;
    unsigned short* agg = (unsigned short*)w;  w += (size_t)N * 128 * 2;
    unsigned short* h1  = (unsigned short*)w;  w += (size_t)N * 128 * 2;

    hipMemsetAsync(deg8, 0, (size_t)NREP * N * 4, stream);

    k_deg_cast<<<(N * 64 + 255) / 256, 256, 0, stream>>>(dst, deg8, rank, E, x,
                                                         (unsigned int*)xb, N * 64);
    k_scan1<<<NB, 1024, 0, stream>>>(deg8, psum, N);
    k_scan2<<<1, 128, 0, stream>>>(psum, NB);
    k_scan3<<<NB, 1024, 0, stream>>>(deg8, psum, offs, repb, dinv, N, E);
    k_csr<<<E / 256, 256, 0, stream>>>(src, dst, rank, repb, csr, E);
    k_packAll<<<144, 64, 0, stream>>>(W1l, W1r, W2l, W2r, Wlin, p1, p2, ph);

    // layer 1: h1 = relu([agg|xb] @ [W1l;W1r] + b1)
    k_aggb<<<(N + 3) / 4, 256, 0, stream>>>((const uint4*)xb, offs, csr, dinv,
                                            (uint4*)agg, N);
    k_mfma<8, 8, true, true, false, false, true><<<(N + 63) / 64, 256, 0, stream>>>(
        agg, xb, p1, b1, nullptr, nullptr, nullptr, h1, N);

    // layer 2 + head fused
    k_aggb<<<(N + 3) / 4, 256, 0, stream>>>((const uint4*)h1, offs, csr, dinv,
                                            (uint4*)agg, N);
    k_mfma<8, 8, true, true, true, true, false><<<(N + 63) / 64, 256, 0, stream>>>(
        agg, h1, p2, b2, h1, ph, blin, out, N);
}

// Round 8
// 388.273 us; speedup vs baseline: 2.5241x; 1.1400x over previous
//
#include <hip/hip_runtime.h>
#include <hip/hip_bf16.h>
#include <cstdint>

#define NND 100000
#define NED 1600000
#define FIN 128
#define FOUT 64

// bucket-sort CSR parameters
#define NBLK 512              // histogram/scatter blocks
#define EPB (NED / NBLK)      // 3125 edges per block (exact)
#define NBUCK 256             // coarse buckets
#define BSH 9                 // bucket = dst >> 9
#define BNODES 512            // nodes per bucket
#define HTN (NBUCK * NBLK)    // histT length = 131072

typedef __bf16 bf16x8 __attribute__((ext_vector_type(8)));
typedef float f32x4 __attribute__((ext_vector_type(4)));

static __device__ inline unsigned short f2bf(float f) {
    unsigned int u = __builtin_bit_cast(unsigned int, f);
    unsigned int r = (u + 0x7fffu + ((u >> 16) & 1u)) >> 16;  // RNE
    return (unsigned short)r;
}
static __device__ inline float bflo(unsigned int v) {
    return __builtin_bit_cast(float, v << 16);
}
static __device__ inline float bfhi(unsigned int v) {
    return __builtin_bit_cast(float, v & 0xffff0000u);
}
static __device__ inline float bf1(unsigned short u) {
    return __builtin_bit_cast(float, (unsigned int)u << 16);
}

// ---------------- weight pack into MFMA B-fragment order ----------------
static __device__ inline void pack_one(const float* __restrict__ W,
                                       unsigned short* __restrict__ out,
                                       int NTtot, int c_local, int nt,
                                       int chunkOff, int ncols, int lane) {
    int k = c_local * 32 + (lane >> 4) * 8;
    int n = nt * 16 + (lane & 15);
    unsigned short t[8];
#pragma unroll
    for (int j = 0; j < 8; j++) t[j] = f2bf(W[(size_t)(k + j) * ncols + n]);
    uint4 u;
    u.x = t[0] | ((unsigned)t[1] << 16);
    u.y = t[2] | ((unsigned)t[3] << 16);
    u.z = t[4] | ((unsigned)t[5] << 16);
    u.w = t[6] | ((unsigned)t[7] << 16);
    *(uint4*)&out[((size_t)((c_local + chunkOff) * NTtot + nt) * 64 + lane) * 8] = u;
}

// ---------------- K1: per-block bucket histogram + x cast + weight pack ----
__global__ __launch_bounds__(256) void k_hist_cast(
        const int* __restrict__ dst, int* __restrict__ histT,
        const float* __restrict__ x, unsigned int* __restrict__ xb,
        const float* W1l, const float* W1r, const float* W2l,
        const float* W2r, const float* Wlin,
        unsigned short* p1, unsigned short* p2, unsigned short* ph) {
    __shared__ int hist[NBUCK];
    const int tid = threadIdx.x, blk = blockIdx.x;
    hist[tid] = 0;  // 256 threads == NBUCK
    __syncthreads();
    const int e0 = blk * EPB, e1 = e0 + EPB;
    for (int i = e0 + tid; i < e1; i += 256)
        atomicAdd(&hist[dst[i] >> BSH], 1);   // LDS atomic
    __syncthreads();
    histT[tid * NBLK + blk] = hist[tid];
    // fused weight pack (blocks 0..143, first wave)
    if (blk < 144 && tid < 64) {
        int b = blk, lane = tid;
        if (b < 32)       pack_one(W1l, p1, 8, b >> 3, b & 7, 0, 128, lane);
        else if (b < 64)  { b -= 32; pack_one(W1r, p1, 8, b >> 3, b & 7, 4, 128, lane); }
        else if (b < 96)  { b -= 64; pack_one(W2l, p2, 8, b >> 3, b & 7, 0, 128, lane); }
        else if (b < 128) { b -= 96; pack_one(W2r, p2, 8, b >> 3, b & 7, 4, 128, lane); }
        else              { b -= 128; pack_one(Wlin, ph, 4, b >> 2, b & 3, 0, 64, lane); }
    }
    // fused cast: grid-stride over N*64 float2
    const int total2 = NND * 64;
    for (int i = blk * 256 + tid; i < total2; i += NBLK * 256) {
        float2 v = ((const float2*)x)[i];
        xb[i] = (unsigned int)f2bf(v.x) | ((unsigned int)f2bf(v.y) << 16);
    }
}

// ---------------- generic hierarchical exclusive scan (n = HTN) ------------
__global__ __launch_bounds__(1024) void g_scan1(const int* __restrict__ in,
                                                int* __restrict__ psum, int n) {
    __shared__ int red[1024];
    int tid = threadIdx.x;
    int i = blockIdx.x * 1024 + tid;
    red[tid] = (i < n) ? in[i] : 0;
    __syncthreads();
#pragma unroll
    for (int off = 512; off > 0; off >>= 1) {
        if (tid < off) red[tid] += red[tid + off];
        __syncthreads();
    }
    if (tid == 0) psum[blockIdx.x] = red[0];
}

__global__ __launch_bounds__(128) void g_scan2(int* __restrict__ psum, int nb) {
    int tid = threadIdx.x;
    int d = (tid < nb) ? psum[tid] : 0;
    int v = d;
#pragma unroll
    for (int off = 1; off < 64; off <<= 1) {
        int u = __shfl_up(v, off, 64);
        if ((tid & 63) >= off) v += u;
    }
    __shared__ int ws[2];
    if ((tid & 63) == 63) ws[tid >> 6] = v;
    __syncthreads();
    int base = (tid >= 64) ? ws[0] : 0;
    if (tid < nb) psum[tid] = base + v - d;
}

__global__ __launch_bounds__(1024) void g_scan3(const int* __restrict__ in,
                                                const int* __restrict__ psum,
                                                int* __restrict__ out, int n) {
    int tid = threadIdx.x;
    int i = blockIdx.x * 1024 + tid;
    int d = (i < n) ? in[i] : 0;
    int v = d;
#pragma unroll
    for (int off = 1; off < 64; off <<= 1) {
        int u = __shfl_up(v, off, 64);
        if ((tid & 63) >= off) v += u;
    }
    __shared__ int wsum[16];
    int wid = tid >> 6;
    if ((tid & 63) == 63) wsum[wid] = v;
    __syncthreads();
    if (tid < 16) {
        int w = wsum[tid];
#pragma unroll
        for (int off = 1; off < 16; off <<= 1) {
            int u = __shfl_up(w, off, 64);
            if (tid >= off) w += u;
        }
        wsum[tid] = w;
    }
    __syncthreads();
    int base = psum[blockIdx.x] + (wid ? wsum[wid - 1] : 0);
    if (i < n) out[i] = base + v - d;
}

// ---------------- K3: coarse scatter into bucket-grouped pairs -------------
__global__ __launch_bounds__(256) void k_scatter(const int* __restrict__ src,
                                                 const int* __restrict__ dst,
                                                 const int* __restrict__ sh,
                                                 uint2* __restrict__ eS) {
    __shared__ int cur[NBUCK];
    const int tid = threadIdx.x, blk = blockIdx.x;
    cur[tid] = sh[tid * NBLK + blk];
    __syncthreads();
    const int e0 = blk * EPB, e1 = e0 + EPB;
    for (int i = e0 + tid; i < e1; i += 256) {
        int d = dst[i];
        int pos = atomicAdd(&cur[d >> BSH], 1);   // LDS atomic
        eS[pos] = make_uint2((unsigned)src[i], (unsigned)(d & (BNODES - 1)));
    }
}

// ---------------- K4: per-bucket counting sort -> csr, offs, dinv ----------
__global__ __launch_bounds__(1024) void k_bucket(const uint2* __restrict__ eS,
                                                 const int* __restrict__ sh,
                                                 int* __restrict__ csr,
                                                 int* __restrict__ offs,
                                                 float* __restrict__ dinv, int n) {
    __shared__ int cnt[BNODES];
    __shared__ int loc[BNODES];
    const int b = blockIdx.x, tid = threadIdx.x;
    const int base = sh[b * NBLK];
    const int end = (b == NBUCK - 1) ? NED : sh[(b + 1) * NBLK];
    if (tid < BNODES) cnt[tid] = 0;
    __syncthreads();
    for (int i = base + tid; i < end; i += 1024)
        atomicAdd(&cnt[eS[i].y], 1);              // LDS atomic
    __syncthreads();
    // inclusive Hillis-Steele scan of cnt -> loc
    if (tid < BNODES) loc[tid] = cnt[tid];
    __syncthreads();
#pragma unroll
    for (int off = 1; off < BNODES; off <<= 1) {
        int v = 0;
        if (tid < BNODES && tid >= off) v = loc[tid - off];
        __syncthreads();
        if (tid < BNODES) loc[tid] += v;
        __syncthreads();
    }
    int node = b * BNODES + tid;
    int myExcl = 0;
    if (tid < BNODES) {
        myExcl = loc[tid] - cnt[tid];  // exclusive
        if (node < n) {
            offs[node] = base + myExcl;
            dinv[node] = 1.0f / fmaxf((float)cnt[tid], 1.0f);
        }
    }
    __syncthreads();
    if (tid < BNODES) cnt[tid] = base + myExcl;  // running cursor
    __syncthreads();
    for (int i = base + tid; i < end; i += 1024) {
        uint2 e = eS[i];
        int slot = atomicAdd(&cnt[e.y], 1);       // LDS atomic
        csr[slot] = (int)e.x;
    }
    if (b == 0 && tid == 0) offs[n] = NED;
}

// ---------------- mean-aggregate: wave/node, 16 edges in flight ------------
#define ACC8(v) do { \
    acc[0].x += bflo((v).x); acc[0].y += bfhi((v).x); \
    acc[1].x += bflo((v).y); acc[1].y += bfhi((v).y); \
    acc[2].x += bflo((v).z); acc[2].y += bfhi((v).z); \
    acc[3].x += bflo((v).w); acc[3].y += bfhi((v).w); } while (0)

__global__ __launch_bounds__(256) void k_aggb(const uint4* __restrict__ feat4,
                                              const int* __restrict__ offs,
                                              const int* __restrict__ csr,
                                              const float* __restrict__ dinv,
                                              uint4* __restrict__ out4, int n) {
    int node = blockIdx.x * 4 + (threadIdx.x >> 6);
    if (node >= n) return;
    int lane = threadIdx.x & 63;
    int grp = lane >> 4;
    int ch = lane & 15;
    int beg = offs[node], end = offs[node + 1];
    int deg = end - beg;

    float2 acc[4];
#pragma unroll
    for (int j = 0; j < 4; j++) acc[j] = make_float2(0.f, 0.f);

    int i = beg;
    int fullEnd = beg + (deg & ~15);
    for (; i < fullEnd; i += 16) {
        int s0 = csr[i + grp];
        int s1 = csr[i + 4 + grp];
        int s2 = csr[i + 8 + grp];
        int s3 = csr[i + 12 + grp];
        uint4 v0 = feat4[(size_t)s0 * 16 + ch];
        uint4 v1 = feat4[(size_t)s1 * 16 + ch];
        uint4 v2 = feat4[(size_t)s2 * 16 + ch];
        uint4 v3 = feat4[(size_t)s3 * 16 + ch];
        ACC8(v0); ACC8(v1); ACC8(v2); ACC8(v3);
    }
    if (i < end) {
#pragma unroll
        for (int g = 0; g < 4; g++) {
            int e = i + g * 4 + grp;
            bool p = e < end;
            int s = csr[p ? e : beg];
            uint4 v = feat4[(size_t)s * 16 + ch];
            if (p) { ACC8(v); }
        }
    }
#pragma unroll
    for (int j = 0; j < 4; j++) {
        acc[j].x += __shfl_xor(acc[j].x, 16);
        acc[j].y += __shfl_xor(acc[j].y, 16);
        acc[j].x += __shfl_xor(acc[j].x, 32);
        acc[j].y += __shfl_xor(acc[j].y, 32);
    }
    if (grp == 0) {
        float di = dinv[node];
        uint4 o;
        o.x = (unsigned)f2bf(acc[0].x * di) | ((unsigned)f2bf(acc[0].y * di) << 16);
        o.y = (unsigned)f2bf(acc[1].x * di) | ((unsigned)f2bf(acc[1].y * di) << 16);
        o.z = (unsigned)f2bf(acc[2].x * di) | ((unsigned)f2bf(acc[2].y * di) << 16);
        o.w = (unsigned)f2bf(acc[3].x * di) | ((unsigned)f2bf(acc[3].y * di) << 16);
        out4[(size_t)node * 16 + ch] = o;
    }
}

// ---------------- MFMA GEMM (+optional fused head) ----------------
template <int NT, int KCH, bool TWO, bool RELU, bool RESID, bool HEAD, bool OUTBF>
__global__ __launch_bounds__(256) void k_mfma(const unsigned short* __restrict__ P,
                                              const unsigned short* __restrict__ Q,
                                              const unsigned short* __restrict__ Wp,
                                              const float* __restrict__ bias,
                                              const unsigned short* __restrict__ resid,
                                              const unsigned short* __restrict__ Wp2,
                                              const float* __restrict__ bias2,
                                              void* __restrict__ outv, int n) {
    const int lane = threadIdx.x & 63;
    const int wave = threadIdx.x >> 6;
    const int quad = lane >> 4;
    const int row0 = blockIdx.x * 64 + wave * 16;
    int rowA = row0 + (lane & 15);
    if (rowA >= n) rowA = n - 1;

    f32x4 acc[NT];
#pragma unroll
    for (int t = 0; t < NT; t++) acc[t] = (f32x4){0.f, 0.f, 0.f, 0.f};

#pragma unroll
    for (int c = 0; c < KCH; c++) {
        const unsigned short* Abase = (TWO && c >= KCH / 2) ? Q : P;
        const int kk = (TWO ? (c & (KCH / 2 - 1)) : c) * 32 + quad * 8;
        bf16x8 a = *(const bf16x8*)&Abase[(size_t)rowA * 128 + kk];
#pragma unroll
        for (int t = 0; t < NT; t++) {
            bf16x8 b = *(const bf16x8*)&Wp[(size_t)((c * NT + t) * 64 + lane) * 8];
            acc[t] = __builtin_amdgcn_mfma_f32_16x16x32_bf16(a, b, acc[t], 0, 0, 0);
        }
    }

    const int col = lane & 15;
    if (!HEAD) {
#pragma unroll
        for (int t = 0; t < NT; t++) {
            float bv = bias[t * 16 + col];
#pragma unroll
            for (int r = 0; r < 4; r++) {
                int row = row0 + quad * 4 + r;
                if (row < n) {
                    float v = acc[t][r] + bv;
                    if (RESID) v += bf1(resid[(size_t)row * 128 + t * 16 + col]);
                    if (RELU) v = fmaxf(v, 0.f);
                    if (OUTBF)
                        ((unsigned short*)outv)[(size_t)row * (NT * 16) + t * 16 + col] = f2bf(v);
                    else
                        ((float*)outv)[(size_t)row * (NT * 16) + t * 16 + col] = v;
                }
            }
        }
    } else {
        __shared__ __align__(16) unsigned short sT[4][16 * 136];
#pragma unroll
        for (int t = 0; t < NT; t++) {
            float bv = bias[t * 16 + col];
#pragma unroll
            for (int r = 0; r < 4; r++) {
                int row = row0 + quad * 4 + r;
                int rr = row < n ? row : n - 1;
                float v = acc[t][r] + bv;
                if (RESID) v += bf1(resid[(size_t)rr * 128 + t * 16 + col]);
                if (RELU) v = fmaxf(v, 0.f);
                sT[wave][(quad * 4 + r) * 136 + t * 16 + col] = f2bf(v);
            }
        }
        f32x4 hacc[4];
#pragma unroll
        for (int t = 0; t < 4; t++) hacc[t] = (f32x4){0.f, 0.f, 0.f, 0.f};
#pragma unroll
        for (int c = 0; c < 4; c++) {
            bf16x8 a = *(const bf16x8*)&sT[wave][(lane & 15) * 136 + c * 32 + quad * 8];
#pragma unroll
            for (int t = 0; t < 4; t++) {
                bf16x8 b = *(const bf16x8*)&Wp2[(size_t)((c * 4 + t) * 64 + lane) * 8];
                hacc[t] = __builtin_amdgcn_mfma_f32_16x16x32_bf16(a, b, hacc[t], 0, 0, 0);
            }
        }
#pragma unroll
        for (int t = 0; t < 4; t++) {
            float bv = bias2[t * 16 + col];
#pragma unroll
            for (int r = 0; r < 4; r++) {
                int row = row0 + quad * 4 + r;
                if (row < n)
                    ((float*)outv)[(size_t)row * 64 + t * 16 + col] = hacc[t][r] + bv;
            }
        }
    }
}

extern "C" void kernel_launch(void* const* d_in, const int* in_sizes, int n_in,
                              void* d_out, int out_size, void* d_ws, size_t ws_size,
                              hipStream_t stream) {
    const float* x    = (const float*)d_in[0];
    const int*   ei   = (const int*)d_in[1];
    const float* W1l  = (const float*)d_in[2];
    const float* b1   = (const float*)d_in[3];
    const float* W1r  = (const float*)d_in[4];
    const float* W2l  = (const float*)d_in[5];
    const float* b2   = (const float*)d_in[6];
    const float* W2r  = (const float*)d_in[7];
    const float* Wlin = (const float*)d_in[8];
    const float* blin = (const float*)d_in[9];
    float* out = (float*)d_out;

    const int N = NND, E = NED;
    const int* src = ei;
    const int* dst = ei + E;
    const int NB2 = HTN / 1024;  // 128 scan blocks

    char* w = (char*)d_ws;
    int*   histT  = (int*)w;               w += (size_t)HTN * 4;
    int*   sh     = (int*)w;               w += (size_t)HTN * 4;
    int*   psum   = (int*)w;               w += (size_t)NB2 * 4;
    int*   offs   = (int*)w;               w += (size_t)(N + 4) * 4;
    float* dinv   = (float*)w;             w += (size_t)N * 4;
    uint2* eS     = (uint2*)w;             w += (size_t)E * 8;
    int*   csr    = (int*)w;               w += (size_t)E * 4;
    unsigned short* p1  = (unsigned short*)w;  w += 256 * 128 * 2;
    unsigned short* p2  = (unsigned short*)w;  w += 256 * 128 * 2;
    unsigned short* ph  = (unsigned short*)w;  w += 128 * 64 * 2;
    unsigned short* xb  = (unsigned short*)w;  w += (size_t)N * 128 * 2;
    unsigned short* agg = (unsigned short*)w;  w += (size_t)N * 128 * 2;
    unsigned short* h1  = (unsigned short*)w;  w += (size_t)N * 128 * 2;

    // CSR build: zero global atomics
    k_hist_cast<<<NBLK, 256, 0, stream>>>(dst, histT, x, (unsigned int*)xb,
                                          W1l, W1r, W2l, W2r, Wlin, p1, p2, ph);
    g_scan1<<<NB2, 1024, 0, stream>>>(histT, psum, HTN);
    g_scan2<<<1, 128, 0, stream>>>(psum, NB2);
    g_scan3<<<NB2, 1024, 0, stream>>>(histT, psum, sh, HTN);
    k_scatter<<<NBLK, 256, 0, stream>>>(src, dst, sh, eS);
    k_bucket<<<NBUCK, 1024, 0, stream>>>(eS, sh, csr, offs, dinv, N);

    // layer 1: h1 = relu([agg|xb] @ [W1l;W1r] + b1)
    k_aggb<<<(N + 3) / 4, 256, 0, stream>>>((const uint4*)xb, offs, csr, dinv,
                                            (uint4*)agg, N);
    k_mfma<8, 8, true, true, false, false, true><<<(N + 63) / 64, 256, 0, stream>>>(
        agg, xb, p1, b1, nullptr, nullptr, nullptr, h1, N);

    // layer 2 + head fused
    k_aggb<<<(N + 3) / 4, 256, 0, stream>>>((const uint4*)h1, offs, csr, dinv,
                                            (uint4*)agg, N);
    k_mfma<8, 8, true, true, true, true, false><<<(N + 63) / 64, 256, 0, stream>>>(
        agg, h1, p2, b2, h1, ph, blin, out, N);
}